// Round 3
// baseline (2468.233 us; speedup 1.0000x reference)
//
#include <hip/hip_runtime.h>
#include <hip/hip_bf16.h>
#include <stdint.h>

#define N_TOK 4096
#define D_ 1024
#define H_ 4096
#define E_ 8
#define NSLOT (N_TOK*2)
#define BM 128
#define BN 128
#define BK 32
#define MAXT 72
// 256^2 gemm params
#define BM2 256
#define BN2 256
#define BK2 32
#define MAXT2 40

typedef __attribute__((ext_vector_type(8))) short short8;
typedef __attribute__((ext_vector_type(4))) float floatx4;
typedef unsigned int u32;

__device__ __forceinline__ unsigned short f2bf(float f){
    union { float f; unsigned int u; } c; c.f = f;
    unsigned int u = c.u;
    unsigned int r = (u + 0x7fffu + ((u >> 16) & 1u)) >> 16;  // RNE
    return (unsigned short)r;
}

__device__ __forceinline__ void async16(const void* g, void* l){
    __builtin_amdgcn_global_load_lds(
        (const __attribute__((address_space(1))) u32*)g,
        (__attribute__((address_space(3))) u32*)l, 16, 0, 0);
}

// ---------------- fp32 -> bf16 weight conversion -----------------------------
__global__ __launch_bounds__(256) void cvt_kernel(
    const float* __restrict__ src, unsigned short* __restrict__ dst, int n4)
{
    int stride = gridDim.x * 256;
    for (int i = blockIdx.x * 256 + threadIdx.x; i < n4; i += stride){
        float4 v = ((const float4*)src)[i];
        ushort4 o; o.x=f2bf(v.x); o.y=f2bf(v.y); o.z=f2bf(v.z); o.w=f2bf(v.w);
        ((ushort4*)dst)[i] = o;
    }
}

// ---------------- Router: fp32 logits, top-2, softmax(2) ---------------------
__global__ __launch_bounds__(256) void router_kernel(
    const float* __restrict__ x, const float* __restrict__ Wr,
    const float* __restrict__ br, int* __restrict__ topIdx,
    float* __restrict__ topGate)
{
    int n = blockIdx.x * 4 + (threadIdx.x >> 6);
    int lane = threadIdx.x & 63;
    const float4* xp = (const float4*)(x + (size_t)n * D_);
    float acc[E_];
#pragma unroll
    for (int e = 0; e < E_; e++) acc[e] = 0.f;
#pragma unroll
    for (int j = 0; j < 4; j++){
        int idx = j * 64 + lane;
        float4 xv = xp[idx];
#pragma unroll
        for (int e = 0; e < E_; e++){
            float4 wv = ((const float4*)(Wr + (size_t)e * D_))[idx];
            acc[e] += xv.x*wv.x + xv.y*wv.y + xv.z*wv.z + xv.w*wv.w;
        }
    }
#pragma unroll
    for (int e = 0; e < E_; e++){
        float v = acc[e];
        for (int off = 32; off > 0; off >>= 1) v += __shfl_xor(v, off, 64);
        acc[e] = v;
    }
    if (lane == 0){
        float best = -1e30f, second = -1e30f; int bi = 0, si = 0;
#pragma unroll
        for (int e = 0; e < E_; e++){
            float v = acc[e] + br[e];
            if (v > best){ second = best; si = bi; best = v; bi = e; }
            else if (v > second){ second = v; si = e; }
        }
        float e1 = __expf(second - best);
        float denom = 1.f + e1;
        topIdx[n*2+0] = bi;  topIdx[n*2+1] = si;
        topGate[n*2+0] = 1.f/denom;  topGate[n*2+1] = e1/denom;
    }
}

__global__ __launch_bounds__(256) void hist_kernel(
    const int* __restrict__ topIdx, int* __restrict__ hdr)
{
    __shared__ int c[E_];
    int t = threadIdx.x;
    if (t < E_) c[t] = 0;
    __syncthreads();
    int e = topIdx[blockIdx.x * 256 + t];
    atomicAdd(&c[e], 1);
    __syncthreads();
    if (t < E_) hdr[256 + blockIdx.x * E_ + t] = c[t];
}

__global__ __launch_bounds__(64) void scan2_kernel(int* __restrict__ hdr)
{
    __shared__ int cnt[32 * E_];
    __shared__ int tot[E_];
    __shared__ int offs[E_ + 1];
    int t = threadIdx.x;
    for (int i = t; i < 32 * E_; i += 64) cnt[i] = hdr[256 + i];
    __syncthreads();
    if (t < E_){
        int s = 0;
        for (int b = 0; b < 32; b++) s += cnt[b * E_ + t];
        tot[t] = s;
    }
    __syncthreads();
    if (t == 0){
        int o = 0;
        for (int e = 0; e < E_; e++){ offs[e] = o; o += tot[e]; }
        offs[E_] = o;
    }
    __syncthreads();
    if (t < E_ + 1) hdr[16 + t] = offs[t];
    if (t < E_){
        int run = offs[t];
        for (int b = 0; b < 32; b++){ hdr[512 + b * E_ + t] = run; run += cnt[b * E_ + t]; }
    }
    if (t == 0){
        // 128-row tiles (fallback path)
        int tn = 0;
        for (int e = 0; e < E_; e++){
            int nt = (tot[e] + BM - 1) >> 7;
            for (int i = 0; i < nt; i++){ hdr[32 + tn] = e; hdr[112 + tn] = offs[e] + (i << 7); tn++; }
        }
        for (; tn < MAXT; tn++){ hdr[32 + tn] = -1; hdr[112 + tn] = 0; }
        // 256-row tiles (main path)
        int t2 = 0;
        for (int e = 0; e < E_; e++){
            int nt = (tot[e] + BM2 - 1) >> 8;
            for (int i = 0; i < nt; i++){ hdr[768 + t2] = e; hdr[808 + t2] = offs[e] + (i << 8); t2++; }
        }
        for (; t2 < MAXT2; t2++){ hdr[768 + t2] = -1; hdr[808 + t2] = 0; }
    }
}

__global__ __launch_bounds__(256) void pos_kernel(
    const int* __restrict__ topIdx, const float* __restrict__ topGate,
    const int* __restrict__ hdr, int* __restrict__ posOf,
    int* __restrict__ rowTok, float* __restrict__ rowGate)
{
    __shared__ int c[E_];
    int t = threadIdx.x;
    if (t < E_) c[t] = 0;
    __syncthreads();
    int slot = blockIdx.x * 256 + t;
    int e = topIdx[slot];
    int r = atomicAdd(&c[e], 1);
    int pos = hdr[512 + blockIdx.x * E_ + e] + r;
    posOf[slot] = pos;
    rowTok[pos] = slot >> 1;
    rowGate[pos] = topGate[slot];
}

__global__ __launch_bounds__(256) void copy_kernel(
    const float* __restrict__ x, const int* __restrict__ posOf,
    unsigned short* __restrict__ xg)
{
    int slot = blockIdx.x * 4 + (threadIdx.x >> 6);
    int lane = threadIdx.x & 63;
    int n = slot >> 1;
    int pos = posOf[slot];
    const float4* xp = (const float4*)(x + (size_t)n * D_);
    ushort4* op = (ushort4*)(xg + (size_t)pos * D_);
#pragma unroll
    for (int j = 0; j < 4; j++){
        float4 v = xp[j * 64 + lane];
        ushort4 o; o.x=f2bf(v.x); o.y=f2bf(v.y); o.z=f2bf(v.z); o.w=f2bf(v.w);
        op[j * 64 + lane] = o;
    }
}

// ============================================================================
// 256x256 grouped GEMM (bf16), classic 2-phase double-buffer (m248 "2ph"
// structure, measured 655-682 TF on grouped 256^2 K=1024):
//   - 512 thr = 8 waves (2M x 4N), per-wave output 128x64, acc[8][4]
//   - BK=32, 2 LDS buffers -> 64 KiB -> 2 blocks/CU (16 waves/CU). The
//     syncthreads vmcnt-drain per iter is hidden by inter-block overlap
//     (m114 mechanism) -- this is what made the 128^2/32KB version fast and
//     the 128KiB 4-ring version slow (1 block/CU, nothing to overlap with).
//   - one __syncthreads per K-step; issue next tile right after it.
//   - XOR granule swizzle g^((r>>1)&3): verified 0 bank conflicts (round 2).
//   - setprio(1) around the MFMA cluster (T5; arbitrates across the 2 blocks).
// MODE 1: hout = relu(A@W^T+b) bf16.  MODE 2: out[tok] += gate*(A@W^T+b).
// ============================================================================
template<int MODE>
__global__ __launch_bounds__(512, 4) void moe_gemm2(
    const unsigned short* __restrict__ A, int Ktot,
    const unsigned short* __restrict__ Wbase, size_t wStride,
    const float* __restrict__ biasBase, int biasStride,
    const int* __restrict__ hdr,
    const int* __restrict__ rowTok, const float* __restrict__ rowGate,
    unsigned short* __restrict__ hout, float* __restrict__ out)
{
    // bijective XCD-aware remap (m204)
    int nwg  = gridDim.x * gridDim.y * gridDim.z;
    int orig = (blockIdx.z * gridDim.y + blockIdx.y) * gridDim.x + blockIdx.x;
    int xcd = orig & 7, loc = orig >> 3;
    int q8 = nwg >> 3, r8 = nwg & 7;
    int wgid = (xcd < r8 ? xcd * (q8 + 1) : r8 * (q8 + 1) + (xcd - r8) * q8) + loc;
    int bx = wgid % gridDim.x;
    int tt = wgid / gridDim.x;
    int by = tt % gridDim.y;
    int bz = tt / gridDim.y;

    int e = hdr[768 + bx];
    if (e < 0) return;
    int rowBase = hdr[808 + bx];
    int validRows = hdr[16 + e + 1] - rowBase;

    int kChunk = Ktot / gridDim.z;
    int kStart = bz * kChunk;
    int nIter  = kChunk / BK2;

    __shared__ __align__(16) unsigned short As[2][BM2 * BK2];   // 2 x 16 KB
    __shared__ __align__(16) unsigned short Bs[2][BN2 * BK2];   // 2 x 16 KB

    const int tid  = threadIdx.x;
    const int lane = tid & 63, wave = tid >> 6;
    const int wm = wave >> 2, wn = wave & 3;     // 2 x 4 wave grid
    const int l16 = lane & 15, quad = lane >> 4;

    const unsigned short* Wexp = Wbase + (size_t)e * wStride + (size_t)(by * BN2) * Ktot;

    // staging descriptors: 2 x 16B granules per thread per operand per K-tile
    u32 aOff[2], bOff[2], lOff[2];
#pragma unroll
    for (int i = 0; i < 2; i++){
        int s = i * 512 + tid;
        int rr = s >> 2, gst = s & 3;
        int gsrc = gst ^ ((rr >> 1) & 3);       // pre-swizzled source granule
        int ar = rowBase + rr; ar = ar < (NSLOT - 1) ? ar : (NSLOT - 1);
        aOff[i] = (u32)ar * (u32)Ktot + (u32)(gsrc * 8);
        bOff[i] = (u32)rr * (u32)Ktot + (u32)(gsrc * 8);
        lOff[i] = (u32)(s * 16);
    }

    floatx4 acc[8][4];
#pragma unroll
    for (int mi = 0; mi < 8; mi++)
#pragma unroll
        for (int ni = 0; ni < 4; ni++)
            acc[mi][ni] = (floatx4){0.f, 0.f, 0.f, 0.f};

    const int pg    = quad ^ ((l16 >> 1) & 3);             // swizzled read granule
    const int aFrag = (wm * 128 + l16) * 32 + pg * 8;      // ushort index
    const int bFrag = (wn * 64  + l16) * 32 + pg * 8;

    // prologue: tile 0 -> buffer 0
#pragma unroll
    for (int i = 0; i < 2; i++){
        async16(A    + aOff[i] + kStart, (char*)As[0] + lOff[i]);
        async16(Wexp + bOff[i] + kStart, (char*)Bs[0] + lOff[i]);
    }

    for (int it = 0; it < nIter; it++){
        __syncthreads();                       // buffer p ready (vmcnt drain)
        int p = it & 1;
        if (it + 1 < nIter){
            int kn = kStart + (it + 1) * BK2;
#pragma unroll
            for (int i = 0; i < 2; i++){
                async16(A    + aOff[i] + kn, (char*)As[p ^ 1] + lOff[i]);
                async16(Wexp + bOff[i] + kn, (char*)Bs[p ^ 1] + lOff[i]);
            }
        }
        short8 af[8], bfr[4];
#pragma unroll
        for (int mi = 0; mi < 8; mi++)
            af[mi] = *(const short8*)(As[p] + aFrag + mi * 512);
#pragma unroll
        for (int ni = 0; ni < 4; ni++)
            bfr[ni] = *(const short8*)(Bs[p] + bFrag + ni * 512);
        __builtin_amdgcn_s_setprio(1);
#pragma unroll
        for (int mi = 0; mi < 8; mi++)
#pragma unroll
            for (int ni = 0; ni < 4; ni++)
                acc[mi][ni] = __builtin_amdgcn_mfma_f32_16x16x32_bf16(
                    af[mi], bfr[ni], acc[mi][ni], 0, 0, 0);
        __builtin_amdgcn_s_setprio(0);
    }

    // ---- epilogue
    bool addB = (MODE == 1) || (bz == 0);
    const float* biasE = biasBase + (size_t)e * biasStride + by * BN2;
    float biasv[4];
#pragma unroll
    for (int ni = 0; ni < 4; ni++)
        biasv[ni] = addB ? biasE[wn * 64 + ni * 16 + l16] : 0.f;

#pragma unroll
    for (int mi = 0; mi < 8; mi++){
#pragma unroll
        for (int r2 = 0; r2 < 4; r2++){
            int rl = wm * 128 + mi * 16 + quad * 4 + r2;
            if (rl >= validRows) continue;
            int grow = rowBase + rl;
            int tok = 0; float gate = 0.f;
            if (MODE == 2){ tok = rowTok[grow]; gate = rowGate[grow]; }
#pragma unroll
            for (int ni = 0; ni < 4; ni++){
                int gcol = by * BN2 + wn * 64 + ni * 16 + l16;
                float v = acc[mi][ni][r2] + biasv[ni];
                if (MODE == 1){
                    v = v > 0.f ? v : 0.f;
                    hout[(size_t)grow * H_ + gcol] = f2bf(v);
                } else {
                    atomicAdd(out + (size_t)tok * D_ + gcol, gate * v);
                }
            }
        }
    }
}

// ---------------- legacy 128^2 grouped GEMM (fp32-weight fallback only) ------
template<int MODE, bool BF16B>
__global__ __launch_bounds__(256) void moe_gemm(
    const unsigned short* __restrict__ A, int Ktot,
    const void* __restrict__ Wbase, size_t wStride,
    const float* __restrict__ biasBase, int biasStride,
    const int* __restrict__ hdr,
    const int* __restrict__ rowTok, const float* __restrict__ rowGate,
    unsigned short* __restrict__ hout, float* __restrict__ out)
{
    int gid = blockIdx.y * gridDim.x + blockIdx.x;
    int per = gridDim.x * 8;
    int g = gid / per, rr = gid % per;
    int by = g * 8 + (rr & 7);
    int bx = rr >> 3;

    int e = hdr[32 + bx];
    if (e < 0) return;
    int rowBase = hdr[112 + bx];
    int validRows = hdr[16 + e + 1] - rowBase;

    int kChunk = Ktot / gridDim.z;
    int kStart = blockIdx.z * kChunk;

    __shared__ __align__(16) unsigned short As[2][BM * BK];
    __shared__ __align__(16) unsigned short BsH[BF16B ? 2 * BN * BK : 1];
    __shared__ __align__(16) float BsF[BF16B ? 1 : BN * BK];

    const float* biasE = biasBase + (size_t)e * biasStride + by * BN;

    const int tid  = threadIdx.x;
    const int lane = tid & 63, wave = tid >> 6;
    const int wm = wave & 1, wn = wave >> 1;
    const int l16 = lane & 15, quad = lane >> 4;

    floatx4 acc[4][4];
#pragma unroll
    for (int mi = 0; mi < 4; mi++)
#pragma unroll
        for (int ni = 0; ni < 4; ni++)
            acc[mi][ni] = (floatx4){0.f,0.f,0.f,0.f};

    if (BF16B){
        const unsigned short* Wexp = (const unsigned short*)Wbase
            + (size_t)e * wStride + (size_t)(by * BN) * Ktot;
        size_t aOff[2], bOff[2];
        int    lOff[2];
#pragma unroll
        for (int i = 0; i < 2; i++){
            int s = i * 256 + tid;
            int r = s >> 2, gst = s & 3;
            int gsrc = gst ^ ((r >> 1) & 3);
            int ar = rowBase + r;
            ar = ar < (NSLOT - 1) ? ar : (NSLOT - 1);
            aOff[i] = (size_t)ar * Ktot + gsrc * 8;
            bOff[i] = (size_t)r  * Ktot + gsrc * 8;
            lOff[i] = s * 16;
        }
#pragma unroll
        for (int i = 0; i < 2; i++){
            async16(A    + aOff[i] + kStart, (char*)As[0]  + lOff[i]);
            async16(Wexp + bOff[i] + kStart, (char*)BsH    + lOff[i]);
        }
        int nIter = kChunk / BK;
        for (int it = 0; it < nIter; it++){
            __syncthreads();
            int p = it & 1;
            if (it + 1 < nIter){
                int kn = kStart + (it + 1) * BK;
#pragma unroll
                for (int i = 0; i < 2; i++){
                    async16(A    + aOff[i] + kn, (char*)As[p ^ 1] + lOff[i]);
                    async16(Wexp + bOff[i] + kn, (char*)BsH + (p ^ 1) * (BN * BK * 2) + lOff[i]);
                }
            }
            short8 af[4], bfr[4];
#pragma unroll
            for (int mi = 0; mi < 4; mi++){
                int r = wm*64 + mi*16 + l16;
                int gq = quad ^ ((r >> 1) & 3);
                af[mi] = *(const short8*)(As[p] + r * BK + gq * 8);
            }
#pragma unroll
            for (int ni = 0; ni < 4; ni++){
                int n = wn*64 + ni*16 + l16;
                int gq = quad ^ ((n >> 1) & 3);
                bfr[ni] = *(const short8*)(BsH + p * (BN * BK) + n * BK + gq * 8);
            }
#pragma unroll
            for (int mi = 0; mi < 4; mi++)
#pragma unroll
                for (int ni = 0; ni < 4; ni++)
                    acc[mi][ni] = __builtin_amdgcn_mfma_f32_16x16x32_bf16(
                        af[mi], bfr[ni], acc[mi][ni], 0, 0, 0);
        }
    } else {
        const float* Wexp = (const float*)Wbase
            + (size_t)e * wStride + (size_t)(by * BN) * Ktot;
        int aS[2], aRow[2], aCol[2];
#pragma unroll
        for (int i = 0; i < 2; i++){
            int s = i * 256 + tid;
            aS[i] = s;
            int r = rowBase + (s >> 2);
            aRow[i] = r < (NSLOT - 1) ? r : (NSLOT - 1);
            aCol[i] = (s & 3) * 8;
        }
        int bS[4], bRow[4], bCol[4];
#pragma unroll
        for (int i = 0; i < 4; i++){
            int s = i * 256 + tid;
            bS[i] = s;
            int r = s >> 3, c = s & 7;
            bRow[i] = r;
            bCol[i] = (c ^ (r & 7)) * 4;
        }
        for (int k0 = kStart; k0 < kStart + kChunk; k0 += BK){
#pragma unroll
            for (int i = 0; i < 2; i++)
                async16(A + (size_t)aRow[i] * Ktot + k0 + aCol[i], (char*)As[0] + aS[i] * 16);
#pragma unroll
            for (int i = 0; i < 4; i++)
                async16(Wexp + (size_t)bRow[i] * Ktot + k0 + bCol[i], (char*)BsF + bS[i] * 16);
            __syncthreads();
            short8 af[4], bfr[4];
#pragma unroll
            for (int mi = 0; mi < 4; mi++)
                af[mi] = *(const short8*)(As[0] + (wm*64 + mi*16 + l16) * BK + quad * 8);
#pragma unroll
            for (int ni = 0; ni < 4; ni++){
                int n = wn*64 + ni*16 + l16;
                int g0 = (2*quad)     ^ (n & 7);
                int g1 = (2*quad + 1) ^ (n & 7);
                float4 u0 = *(const float4*)(BsF + n * BK + g0 * 4);
                float4 u1 = *(const float4*)(BsF + n * BK + g1 * 4);
                union { short8 s; __hip_bfloat162 h[4]; } u;
                u.h[0] = __float22bfloat162_rn(make_float2(u0.x, u0.y));
                u.h[1] = __float22bfloat162_rn(make_float2(u0.z, u0.w));
                u.h[2] = __float22bfloat162_rn(make_float2(u1.x, u1.y));
                u.h[3] = __float22bfloat162_rn(make_float2(u1.z, u1.w));
                bfr[ni] = u.s;
            }
#pragma unroll
            for (int mi = 0; mi < 4; mi++)
#pragma unroll
                for (int ni = 0; ni < 4; ni++)
                    acc[mi][ni] = __builtin_amdgcn_mfma_f32_16x16x32_bf16(
                        af[mi], bfr[ni], acc[mi][ni], 0, 0, 0);
            __syncthreads();
        }
    }

    bool addB = (MODE == 1) || (blockIdx.z == 0);
#pragma unroll
    for (int mi = 0; mi < 4; mi++){
#pragma unroll
        for (int r = 0; r < 4; r++){
            int rl = wm*64 + mi*16 + quad*4 + r;
            if (rl >= validRows) continue;
            int grow = rowBase + rl;
            int   tok  = 0;
            float gate = 0.f;
            if (MODE == 2){ tok = rowTok[grow]; gate = rowGate[grow]; }
#pragma unroll
            for (int ni = 0; ni < 4; ni++){
                int lcol = wn*64 + ni*16 + l16;
                int gcol = by * BN + lcol;
                float v = acc[mi][ni][r] + (addB ? biasE[lcol] : 0.f);
                if (MODE == 1){
                    v = v > 0.f ? v : 0.f;
                    hout[(size_t)grow * H_ + gcol] = f2bf(v);
                } else {
                    atomicAdd(out + (size_t)tok * D_ + gcol, gate * v);
                }
            }
        }
    }
}

// ---------------- launch -----------------------------------------------------
extern "C" void kernel_launch(void* const* d_in, const int* in_sizes, int n_in,
                              void* d_out, int out_size, void* d_ws, size_t ws_size,
                              hipStream_t stream)
{
    (void)in_sizes; (void)n_in;
    const float* x  = (const float*)d_in[0];
    const float* Wr = (const float*)d_in[1];
    const float* br = (const float*)d_in[2];
    const float* W1 = (const float*)d_in[3];
    const float* b1 = (const float*)d_in[4];
    const float* W2 = (const float*)d_in[5];
    const float* b2 = (const float*)d_in[6];
    float* out = (float*)d_out;

    char* ws = (char*)d_ws;
    int*   hdr     = (int*)ws;
    int*   topIdx  = (int*)  (ws + 4096);
    float* topGate = (float*)(ws + 36864);
    int*   posOf   = (int*)  (ws + 69632);
    int*   rowTok  = (int*)  (ws + 102400);
    float* rowGate = (float*)(ws + 135168);
    unsigned short* xg   = (unsigned short*)(ws + 262144);     // 16.78 MB
    unsigned short* hbuf = (unsigned short*)(ws + 17039360);   // 67.1 MB
    unsigned short* w1b  = (unsigned short*)(ws + 84148224);   // 67.1 MB
    unsigned short* w2b  = (unsigned short*)(ws + 151257088);  // 67.1 MB -> ends 218365952
    const bool full = ws_size >= 218365952ull;

    hipMemsetAsync(d_out, 0, (size_t)out_size * sizeof(float), stream);

    router_kernel<<<N_TOK/4, 256, 0, stream>>>(x, Wr, br, topIdx, topGate);
    hist_kernel<<<32, 256, 0, stream>>>(topIdx, hdr);
    scan2_kernel<<<1, 64, 0, stream>>>(hdr);
    pos_kernel<<<32, 256, 0, stream>>>(topIdx, topGate, hdr, posOf, rowTok, rowGate);
    copy_kernel<<<NSLOT/4, 256, 0, stream>>>(x, posOf, xg);

    if (full){
        cvt_kernel<<<2048, 256, 0, stream>>>(W1, w1b, (E_*H_*D_)/4);
        cvt_kernel<<<2048, 256, 0, stream>>>(W2, w2b, (E_*D_*H_)/4);
        moe_gemm2<1><<<dim3(MAXT2, H_/BN2, 1), 512, 0, stream>>>(
            xg, D_, w1b, (size_t)H_ * D_, b1, H_, hdr, rowTok, rowGate, hbuf, nullptr);
        moe_gemm2<2><<<dim3(MAXT2, D_/BN2, 4), 512, 0, stream>>>(
            hbuf, H_, w2b, (size_t)D_ * H_, b2, D_, hdr, rowTok, rowGate, nullptr, out);
    } else {
        moe_gemm<1,false><<<dim3(MAXT, H_/BN, 1), 256, 0, stream>>>(
            xg, D_, W1, (size_t)H_ * D_, b1, H_, hdr, rowTok, rowGate, hbuf, nullptr);
        moe_gemm<2,false><<<dim3(MAXT, D_/BN, 2), 256, 0, stream>>>(
            hbuf, H_, W2, (size_t)D_ * H_, b2, D_, hdr, rowTok, rowGate, nullptr, out);
    }
}

// Round 4
// 700.737 us; speedup vs baseline: 3.5223x; 3.5223x over previous
//
#include <hip/hip_runtime.h>
#include <hip/hip_bf16.h>
#include <stdint.h>

#define N_TOK 4096
#define D_ 1024
#define H_ 4096
#define E_ 8
#define NSLOT (N_TOK*2)
#define BM 128
#define BN 128
#define BK 32
#define MAXT 72
// 256^2 gemm params
#define BM2 256
#define BN2 256
#define BK2 32
#define MAXT2 40

typedef __attribute__((ext_vector_type(8))) short short8;
typedef __attribute__((ext_vector_type(4))) float floatx4;
typedef unsigned int u32;

__device__ __forceinline__ unsigned short f2bf(float f){
    union { float f; unsigned int u; } c; c.f = f;
    unsigned int u = c.u;
    unsigned int r = (u + 0x7fffu + ((u >> 16) & 1u)) >> 16;  // RNE
    return (unsigned short)r;
}

__device__ __forceinline__ void async16(const void* g, void* l){
    __builtin_amdgcn_global_load_lds(
        (const __attribute__((address_space(1))) u32*)g,
        (__attribute__((address_space(3))) u32*)l, 16, 0, 0);
}

// ---------------- fp32 -> bf16 weight conversion -----------------------------
__global__ __launch_bounds__(256) void cvt_kernel(
    const float* __restrict__ src, unsigned short* __restrict__ dst, int n4)
{
    int stride = gridDim.x * 256;
    for (int i = blockIdx.x * 256 + threadIdx.x; i < n4; i += stride){
        float4 v = ((const float4*)src)[i];
        ushort4 o; o.x=f2bf(v.x); o.y=f2bf(v.y); o.z=f2bf(v.z); o.w=f2bf(v.w);
        ((ushort4*)dst)[i] = o;
    }
}

// ---------------- Router: fp32 logits, top-2, softmax(2) ---------------------
__global__ __launch_bounds__(256) void router_kernel(
    const float* __restrict__ x, const float* __restrict__ Wr,
    const float* __restrict__ br, int* __restrict__ topIdx,
    float* __restrict__ topGate)
{
    int n = blockIdx.x * 4 + (threadIdx.x >> 6);
    int lane = threadIdx.x & 63;
    const float4* xp = (const float4*)(x + (size_t)n * D_);
    float acc[E_];
#pragma unroll
    for (int e = 0; e < E_; e++) acc[e] = 0.f;
#pragma unroll
    for (int j = 0; j < 4; j++){
        int idx = j * 64 + lane;
        float4 xv = xp[idx];
#pragma unroll
        for (int e = 0; e < E_; e++){
            float4 wv = ((const float4*)(Wr + (size_t)e * D_))[idx];
            acc[e] += xv.x*wv.x + xv.y*wv.y + xv.z*wv.z + xv.w*wv.w;
        }
    }
#pragma unroll
    for (int e = 0; e < E_; e++){
        float v = acc[e];
        for (int off = 32; off > 0; off >>= 1) v += __shfl_xor(v, off, 64);
        acc[e] = v;
    }
    if (lane == 0){
        float best = -1e30f, second = -1e30f; int bi = 0, si = 0;
#pragma unroll
        for (int e = 0; e < E_; e++){
            float v = acc[e] + br[e];
            if (v > best){ second = best; si = bi; best = v; bi = e; }
            else if (v > second){ second = v; si = e; }
        }
        float e1 = __expf(second - best);
        float denom = 1.f + e1;
        topIdx[n*2+0] = bi;  topIdx[n*2+1] = si;
        topGate[n*2+0] = 1.f/denom;  topGate[n*2+1] = e1/denom;
    }
}

__global__ __launch_bounds__(256) void hist_kernel(
    const int* __restrict__ topIdx, int* __restrict__ hdr)
{
    __shared__ int c[E_];
    int t = threadIdx.x;
    if (t < E_) c[t] = 0;
    __syncthreads();
    int e = topIdx[blockIdx.x * 256 + t];
    atomicAdd(&c[e], 1);
    __syncthreads();
    if (t < E_) hdr[256 + blockIdx.x * E_ + t] = c[t];
}

__global__ __launch_bounds__(64) void scan2_kernel(int* __restrict__ hdr)
{
    __shared__ int cnt[32 * E_];
    __shared__ int tot[E_];
    __shared__ int offs[E_ + 1];
    int t = threadIdx.x;
    for (int i = t; i < 32 * E_; i += 64) cnt[i] = hdr[256 + i];
    __syncthreads();
    if (t < E_){
        int s = 0;
        for (int b = 0; b < 32; b++) s += cnt[b * E_ + t];
        tot[t] = s;
    }
    __syncthreads();
    if (t == 0){
        int o = 0;
        for (int e = 0; e < E_; e++){ offs[e] = o; o += tot[e]; }
        offs[E_] = o;
    }
    __syncthreads();
    if (t < E_ + 1) hdr[16 + t] = offs[t];
    if (t < E_){
        int run = offs[t];
        for (int b = 0; b < 32; b++){ hdr[512 + b * E_ + t] = run; run += cnt[b * E_ + t]; }
    }
    if (t == 0){
        // 128-row tiles (fallback path)
        int tn = 0;
        for (int e = 0; e < E_; e++){
            int nt = (tot[e] + BM - 1) >> 7;
            for (int i = 0; i < nt; i++){ hdr[32 + tn] = e; hdr[112 + tn] = offs[e] + (i << 7); tn++; }
        }
        for (; tn < MAXT; tn++){ hdr[32 + tn] = -1; hdr[112 + tn] = 0; }
        // 256-row tiles (main path)
        int t2 = 0;
        for (int e = 0; e < E_; e++){
            int nt = (tot[e] + BM2 - 1) >> 8;
            for (int i = 0; i < nt; i++){ hdr[768 + t2] = e; hdr[808 + t2] = offs[e] + (i << 8); t2++; }
        }
        for (; t2 < MAXT2; t2++){ hdr[768 + t2] = -1; hdr[808 + t2] = 0; }
    }
}

__global__ __launch_bounds__(256) void pos_kernel(
    const int* __restrict__ topIdx, const float* __restrict__ topGate,
    const int* __restrict__ hdr, int* __restrict__ posOf,
    int* __restrict__ rowTok, float* __restrict__ rowGate)
{
    __shared__ int c[E_];
    int t = threadIdx.x;
    if (t < E_) c[t] = 0;
    __syncthreads();
    int slot = blockIdx.x * 256 + t;
    int e = topIdx[slot];
    int r = atomicAdd(&c[e], 1);
    int pos = hdr[512 + blockIdx.x * E_ + e] + r;
    posOf[slot] = pos;
    rowTok[pos] = slot >> 1;
    rowGate[pos] = topGate[slot];
}

__global__ __launch_bounds__(256) void copy_kernel(
    const float* __restrict__ x, const int* __restrict__ posOf,
    unsigned short* __restrict__ xg)
{
    int slot = blockIdx.x * 4 + (threadIdx.x >> 6);
    int lane = threadIdx.x & 63;
    int n = slot >> 1;
    int pos = posOf[slot];
    const float4* xp = (const float4*)(x + (size_t)n * D_);
    ushort4* op = (ushort4*)(xg + (size_t)pos * D_);
#pragma unroll
    for (int j = 0; j < 4; j++){
        float4 v = xp[j * 64 + lane];
        ushort4 o; o.x=f2bf(v.x); o.y=f2bf(v.y); o.z=f2bf(v.z); o.w=f2bf(v.w);
        op[j * 64 + lane] = o;
    }
}

// ============================================================================
// 256x256 grouped GEMM (bf16), classic 2-phase double-buffer (m248 "2ph").
//   - 512 thr = 8 waves (2M x 4N), per-wave output 128x64, acc[8][4]
//   - BK=32, 2 LDS buffers -> 64 KiB -> 2 blocks/CU.
//   - __launch_bounds__(512, 2): round 3's (512,4) halved the register
//     budget -> VGPR_Count 64, acc[8][4] spilled to scratch, 3.6 GB/dispatch
//     HBM traffic, 6x slowdown. (512,2) compiles to 96 VGPR + AGPR acc, no
//     spill (verified rounds 1-2); 64 KiB LDS still allows 2 blocks/CU.
//   - XOR granule swizzle g^((r>>1)&3): verified 0 bank conflicts (round 2).
//   - setprio(1) around the MFMA cluster (T5).
// MODE 1: hout = relu(A@W^T+b) bf16.  MODE 2: out[tok] += gate*(A@W^T+b).
// ============================================================================
template<int MODE>
__global__ __launch_bounds__(512, 2) void moe_gemm2(
    const unsigned short* __restrict__ A, int Ktot,
    const unsigned short* __restrict__ Wbase, size_t wStride,
    const float* __restrict__ biasBase, int biasStride,
    const int* __restrict__ hdr,
    const int* __restrict__ rowTok, const float* __restrict__ rowGate,
    unsigned short* __restrict__ hout, float* __restrict__ out)
{
    // bijective XCD-aware remap (m204)
    int nwg  = gridDim.x * gridDim.y * gridDim.z;
    int orig = (blockIdx.z * gridDim.y + blockIdx.y) * gridDim.x + blockIdx.x;
    int xcd = orig & 7, loc = orig >> 3;
    int q8 = nwg >> 3, r8 = nwg & 7;
    int wgid = (xcd < r8 ? xcd * (q8 + 1) : r8 * (q8 + 1) + (xcd - r8) * q8) + loc;
    int bx = wgid % gridDim.x;
    int tt = wgid / gridDim.x;
    int by = tt % gridDim.y;
    int bz = tt / gridDim.y;

    int e = hdr[768 + bx];
    if (e < 0) return;
    int rowBase = hdr[808 + bx];
    int validRows = hdr[16 + e + 1] - rowBase;

    int kChunk = Ktot / gridDim.z;
    int kStart = bz * kChunk;
    int nIter  = kChunk / BK2;

    __shared__ __align__(16) unsigned short As[2][BM2 * BK2];   // 2 x 16 KB
    __shared__ __align__(16) unsigned short Bs[2][BN2 * BK2];   // 2 x 16 KB

    const int tid  = threadIdx.x;
    const int lane = tid & 63, wave = tid >> 6;
    const int wm = wave >> 2, wn = wave & 3;     // 2 x 4 wave grid
    const int l16 = lane & 15, quad = lane >> 4;

    const unsigned short* Wexp = Wbase + (size_t)e * wStride + (size_t)(by * BN2) * Ktot;

    // staging descriptors: 2 x 16B granules per thread per operand per K-tile
    u32 aOff[2], bOff[2], lOff[2];
#pragma unroll
    for (int i = 0; i < 2; i++){
        int s = i * 512 + tid;
        int rr = s >> 2, gst = s & 3;
        int gsrc = gst ^ ((rr >> 1) & 3);       // pre-swizzled source granule
        int ar = rowBase + rr; ar = ar < (NSLOT - 1) ? ar : (NSLOT - 1);
        aOff[i] = (u32)ar * (u32)Ktot + (u32)(gsrc * 8);
        bOff[i] = (u32)rr * (u32)Ktot + (u32)(gsrc * 8);
        lOff[i] = (u32)(s * 16);
    }

    floatx4 acc[8][4];
#pragma unroll
    for (int mi = 0; mi < 8; mi++)
#pragma unroll
        for (int ni = 0; ni < 4; ni++)
            acc[mi][ni] = (floatx4){0.f, 0.f, 0.f, 0.f};

    const int pg    = quad ^ ((l16 >> 1) & 3);             // swizzled read granule
    const int aFrag = (wm * 128 + l16) * 32 + pg * 8;      // ushort index
    const int bFrag = (wn * 64  + l16) * 32 + pg * 8;

    // prologue: tile 0 -> buffer 0
#pragma unroll
    for (int i = 0; i < 2; i++){
        async16(A    + aOff[i] + kStart, (char*)As[0] + lOff[i]);
        async16(Wexp + bOff[i] + kStart, (char*)Bs[0] + lOff[i]);
    }

    for (int it = 0; it < nIter; it++){
        __syncthreads();                       // buffer p ready (vmcnt drain)
        int p = it & 1;
        if (it + 1 < nIter){
            int kn = kStart + (it + 1) * BK2;
#pragma unroll
            for (int i = 0; i < 2; i++){
                async16(A    + aOff[i] + kn, (char*)As[p ^ 1] + lOff[i]);
                async16(Wexp + bOff[i] + kn, (char*)Bs[p ^ 1] + lOff[i]);
            }
        }
        short8 af[8], bfr[4];
#pragma unroll
        for (int mi = 0; mi < 8; mi++)
            af[mi] = *(const short8*)(As[p] + aFrag + mi * 512);
#pragma unroll
        for (int ni = 0; ni < 4; ni++)
            bfr[ni] = *(const short8*)(Bs[p] + bFrag + ni * 512);
        __builtin_amdgcn_s_setprio(1);
#pragma unroll
        for (int mi = 0; mi < 8; mi++)
#pragma unroll
            for (int ni = 0; ni < 4; ni++)
                acc[mi][ni] = __builtin_amdgcn_mfma_f32_16x16x32_bf16(
                    af[mi], bfr[ni], acc[mi][ni], 0, 0, 0);
        __builtin_amdgcn_s_setprio(0);
    }

    // ---- epilogue
    bool addB = (MODE == 1) || (bz == 0);
    const float* biasE = biasBase + (size_t)e * biasStride + by * BN2;
    float biasv[4];
#pragma unroll
    for (int ni = 0; ni < 4; ni++)
        biasv[ni] = addB ? biasE[wn * 64 + ni * 16 + l16] : 0.f;

#pragma unroll
    for (int mi = 0; mi < 8; mi++){
#pragma unroll
        for (int r2 = 0; r2 < 4; r2++){
            int rl = wm * 128 + mi * 16 + quad * 4 + r2;
            if (rl >= validRows) continue;
            int grow = rowBase + rl;
            int tok = 0; float gate = 0.f;
            if (MODE == 2){ tok = rowTok[grow]; gate = rowGate[grow]; }
#pragma unroll
            for (int ni = 0; ni < 4; ni++){
                int gcol = by * BN2 + wn * 64 + ni * 16 + l16;
                float v = acc[mi][ni][r2] + biasv[ni];
                if (MODE == 1){
                    v = v > 0.f ? v : 0.f;
                    hout[(size_t)grow * H_ + gcol] = f2bf(v);
                } else {
                    atomicAdd(out + (size_t)tok * D_ + gcol, gate * v);
                }
            }
        }
    }
}

// ---------------- legacy 128^2 grouped GEMM (fp32-weight fallback only) ------
template<int MODE, bool BF16B>
__global__ __launch_bounds__(256) void moe_gemm(
    const unsigned short* __restrict__ A, int Ktot,
    const void* __restrict__ Wbase, size_t wStride,
    const float* __restrict__ biasBase, int biasStride,
    const int* __restrict__ hdr,
    const int* __restrict__ rowTok, const float* __restrict__ rowGate,
    unsigned short* __restrict__ hout, float* __restrict__ out)
{
    int gid = blockIdx.y * gridDim.x + blockIdx.x;
    int per = gridDim.x * 8;
    int g = gid / per, rr = gid % per;
    int by = g * 8 + (rr & 7);
    int bx = rr >> 3;

    int e = hdr[32 + bx];
    if (e < 0) return;
    int rowBase = hdr[112 + bx];
    int validRows = hdr[16 + e + 1] - rowBase;

    int kChunk = Ktot / gridDim.z;
    int kStart = blockIdx.z * kChunk;

    __shared__ __align__(16) unsigned short As[2][BM * BK];
    __shared__ __align__(16) unsigned short BsH[BF16B ? 2 * BN * BK : 1];
    __shared__ __align__(16) float BsF[BF16B ? 1 : BN * BK];

    const float* biasE = biasBase + (size_t)e * biasStride + by * BN;

    const int tid  = threadIdx.x;
    const int lane = tid & 63, wave = tid >> 6;
    const int wm = wave & 1, wn = wave >> 1;
    const int l16 = lane & 15, quad = lane >> 4;

    floatx4 acc[4][4];
#pragma unroll
    for (int mi = 0; mi < 4; mi++)
#pragma unroll
        for (int ni = 0; ni < 4; ni++)
            acc[mi][ni] = (floatx4){0.f,0.f,0.f,0.f};

    if (BF16B){
        const unsigned short* Wexp = (const unsigned short*)Wbase
            + (size_t)e * wStride + (size_t)(by * BN) * Ktot;
        size_t aOff[2], bOff[2];
        int    lOff[2];
#pragma unroll
        for (int i = 0; i < 2; i++){
            int s = i * 256 + tid;
            int r = s >> 2, gst = s & 3;
            int gsrc = gst ^ ((r >> 1) & 3);
            int ar = rowBase + r;
            ar = ar < (NSLOT - 1) ? ar : (NSLOT - 1);
            aOff[i] = (size_t)ar * Ktot + gsrc * 8;
            bOff[i] = (size_t)r  * Ktot + gsrc * 8;
            lOff[i] = s * 16;
        }
#pragma unroll
        for (int i = 0; i < 2; i++){
            async16(A    + aOff[i] + kStart, (char*)As[0]  + lOff[i]);
            async16(Wexp + bOff[i] + kStart, (char*)BsH    + lOff[i]);
        }
        int nIter = kChunk / BK;
        for (int it = 0; it < nIter; it++){
            __syncthreads();
            int p = it & 1;
            if (it + 1 < nIter){
                int kn = kStart + (it + 1) * BK;
#pragma unroll
                for (int i = 0; i < 2; i++){
                    async16(A    + aOff[i] + kn, (char*)As[p ^ 1] + lOff[i]);
                    async16(Wexp + bOff[i] + kn, (char*)BsH + (p ^ 1) * (BN * BK * 2) + lOff[i]);
                }
            }
            short8 af[4], bfr[4];
#pragma unroll
            for (int mi = 0; mi < 4; mi++){
                int r = wm*64 + mi*16 + l16;
                int gq = quad ^ ((r >> 1) & 3);
                af[mi] = *(const short8*)(As[p] + r * BK + gq * 8);
            }
#pragma unroll
            for (int ni = 0; ni < 4; ni++){
                int n = wn*64 + ni*16 + l16;
                int gq = quad ^ ((n >> 1) & 3);
                bfr[ni] = *(const short8*)(BsH + p * (BN * BK) + n * BK + gq * 8);
            }
#pragma unroll
            for (int mi = 0; mi < 4; mi++)
#pragma unroll
                for (int ni = 0; ni < 4; ni++)
                    acc[mi][ni] = __builtin_amdgcn_mfma_f32_16x16x32_bf16(
                        af[mi], bfr[ni], acc[mi][ni], 0, 0, 0);
        }
    } else {
        const float* Wexp = (const float*)Wbase
            + (size_t)e * wStride + (size_t)(by * BN) * Ktot;
        int aS[2], aRow[2], aCol[2];
#pragma unroll
        for (int i = 0; i < 2; i++){
            int s = i * 256 + tid;
            aS[i] = s;
            int r = rowBase + (s >> 2);
            aRow[i] = r < (NSLOT - 1) ? r : (NSLOT - 1);
            aCol[i] = (s & 3) * 8;
        }
        int bS[4], bRow[4], bCol[4];
#pragma unroll
        for (int i = 0; i < 4; i++){
            int s = i * 256 + tid;
            bS[i] = s;
            int r = s >> 3, c = s & 7;
            bRow[i] = r;
            bCol[i] = (c ^ (r & 7)) * 4;
        }
        for (int k0 = kStart; k0 < kStart + kChunk; k0 += BK){
#pragma unroll
            for (int i = 0; i < 2; i++)
                async16(A + (size_t)aRow[i] * Ktot + k0 + aCol[i], (char*)As[0] + aS[i] * 16);
#pragma unroll
            for (int i = 0; i < 4; i++)
                async16(Wexp + (size_t)bRow[i] * Ktot + k0 + bCol[i], (char*)BsF + bS[i] * 16);
            __syncthreads();
            short8 af[4], bfr[4];
#pragma unroll
            for (int mi = 0; mi < 4; mi++)
                af[mi] = *(const short8*)(As[0] + (wm*64 + mi*16 + l16) * BK + quad * 8);
#pragma unroll
            for (int ni = 0; ni < 4; ni++){
                int n = wn*64 + ni*16 + l16;
                int g0 = (2*quad)     ^ (n & 7);
                int g1 = (2*quad + 1) ^ (n & 7);
                float4 u0 = *(const float4*)(BsF + n * BK + g0 * 4);
                float4 u1 = *(const float4*)(BsF + n * BK + g1 * 4);
                union { short8 s; __hip_bfloat162 h[4]; } u;
                u.h[0] = __float22bfloat162_rn(make_float2(u0.x, u0.y));
                u.h[1] = __float22bfloat162_rn(make_float2(u0.z, u0.w));
                u.h[2] = __float22bfloat162_rn(make_float2(u1.x, u1.y));
                u.h[3] = __float22bfloat162_rn(make_float2(u1.z, u1.w));
                bfr[ni] = u.s;
            }
#pragma unroll
            for (int mi = 0; mi < 4; mi++)
#pragma unroll
                for (int ni = 0; ni < 4; ni++)
                    acc[mi][ni] = __builtin_amdgcn_mfma_f32_16x16x32_bf16(
                        af[mi], bfr[ni], acc[mi][ni], 0, 0, 0);
            __syncthreads();
        }
    }

    bool addB = (MODE == 1) || (blockIdx.z == 0);
#pragma unroll
    for (int mi = 0; mi < 4; mi++){
#pragma unroll
        for (int r = 0; r < 4; r++){
            int rl = wm*64 + mi*16 + quad*4 + r;
            if (rl >= validRows) continue;
            int grow = rowBase + rl;
            int   tok  = 0;
            float gate = 0.f;
            if (MODE == 2){ tok = rowTok[grow]; gate = rowGate[grow]; }
#pragma unroll
            for (int ni = 0; ni < 4; ni++){
                int lcol = wn*64 + ni*16 + l16;
                int gcol = by * BN + lcol;
                float v = acc[mi][ni][r] + (addB ? biasE[lcol] : 0.f);
                if (MODE == 1){
                    v = v > 0.f ? v : 0.f;
                    hout[(size_t)grow * H_ + gcol] = f2bf(v);
                } else {
                    atomicAdd(out + (size_t)tok * D_ + gcol, gate * v);
                }
            }
        }
    }
}

// ---------------- launch -----------------------------------------------------
extern "C" void kernel_launch(void* const* d_in, const int* in_sizes, int n_in,
                              void* d_out, int out_size, void* d_ws, size_t ws_size,
                              hipStream_t stream)
{
    (void)in_sizes; (void)n_in;
    const float* x  = (const float*)d_in[0];
    const float* Wr = (const float*)d_in[1];
    const float* br = (const float*)d_in[2];
    const float* W1 = (const float*)d_in[3];
    const float* b1 = (const float*)d_in[4];
    const float* W2 = (const float*)d_in[5];
    const float* b2 = (const float*)d_in[6];
    float* out = (float*)d_out;

    char* ws = (char*)d_ws;
    int*   hdr     = (int*)ws;
    int*   topIdx  = (int*)  (ws + 4096);
    float* topGate = (float*)(ws + 36864);
    int*   posOf   = (int*)  (ws + 69632);
    int*   rowTok  = (int*)  (ws + 102400);
    float* rowGate = (float*)(ws + 135168);
    unsigned short* xg   = (unsigned short*)(ws + 262144);     // 16.78 MB
    unsigned short* hbuf = (unsigned short*)(ws + 17039360);   // 67.1 MB
    unsigned short* w1b  = (unsigned short*)(ws + 84148224);   // 67.1 MB
    unsigned short* w2b  = (unsigned short*)(ws + 151257088);  // 67.1 MB -> ends 218365952
    const bool full = ws_size >= 218365952ull;

    hipMemsetAsync(d_out, 0, (size_t)out_size * sizeof(float), stream);

    router_kernel<<<N_TOK/4, 256, 0, stream>>>(x, Wr, br, topIdx, topGate);
    hist_kernel<<<32, 256, 0, stream>>>(topIdx, hdr);
    scan2_kernel<<<1, 64, 0, stream>>>(hdr);
    pos_kernel<<<32, 256, 0, stream>>>(topIdx, topGate, hdr, posOf, rowTok, rowGate);
    copy_kernel<<<NSLOT/4, 256, 0, stream>>>(x, posOf, xg);

    if (full){
        cvt_kernel<<<2048, 256, 0, stream>>>(W1, w1b, (E_*H_*D_)/4);
        cvt_kernel<<<2048, 256, 0, stream>>>(W2, w2b, (E_*D_*H_)/4);
        moe_gemm2<1><<<dim3(MAXT2, H_/BN2, 1), 512, 0, stream>>>(
            xg, D_, w1b, (size_t)H_ * D_, b1, H_, hdr, rowTok, rowGate, hbuf, nullptr);
        moe_gemm2<2><<<dim3(MAXT2, D_/BN2, 4), 512, 0, stream>>>(
            hbuf, H_, w2b, (size_t)D_ * H_, b2, D_, hdr, rowTok, rowGate, nullptr, out);
    } else {
        moe_gemm<1,false><<<dim3(MAXT, H_/BN, 1), 256, 0, stream>>>(
            xg, D_, W1, (size_t)H_ * D_, b1, H_, hdr, rowTok, rowGate, hbuf, nullptr);
        moe_gemm<2,false><<<dim3(MAXT, D_/BN, 2), 256, 0, stream>>>(
            hbuf, H_, W2, (size_t)D_ * H_, b2, D_, hdr, rowTok, rowGate, nullptr, out);
    }
}

// Round 5
// 645.399 us; speedup vs baseline: 3.8244x; 1.0857x over previous
//
#include <hip/hip_runtime.h>
#include <hip/hip_bf16.h>
#include <stdint.h>

#define N_TOK 4096
#define D_ 1024
#define H_ 4096
#define E_ 8
#define NSLOT (N_TOK*2)
#define BM 128
#define BN 128
#define BK 32
#define MAXT 72
// 256^2 gemm params
#define BM2 256
#define BN2 256
#define BK2 32
#define MAXT2 40

typedef __attribute__((ext_vector_type(8))) short short8;
typedef __attribute__((ext_vector_type(4))) float floatx4;
typedef unsigned int u32;

__device__ __forceinline__ unsigned short f2bf(float f){
    union { float f; unsigned int u; } c; c.f = f;
    unsigned int u = c.u;
    unsigned int r = (u + 0x7fffu + ((u >> 16) & 1u)) >> 16;  // RNE
    return (unsigned short)r;
}

__device__ __forceinline__ void async16(const void* g, void* l){
    __builtin_amdgcn_global_load_lds(
        (const __attribute__((address_space(1))) u32*)g,
        (__attribute__((address_space(3))) u32*)l, 16, 0, 0);
}

// sync idiom: no "memory" clobbers (would force compiler vmcnt(0) drains);
// ordering pinned via sched_barrier(0), sync via raw builtin s_barrier,
// hazards via explicit COUNTED waitcnt asm.
__device__ __forceinline__ void sb(){ __builtin_amdgcn_sched_barrier(0); }

// ---------------- fp32 -> bf16 weight conversion -----------------------------
__global__ __launch_bounds__(256) void cvt_kernel(
    const float* __restrict__ src, unsigned short* __restrict__ dst, int n4)
{
    int stride = gridDim.x * 256;
    for (int i = blockIdx.x * 256 + threadIdx.x; i < n4; i += stride){
        float4 v = ((const float4*)src)[i];
        ushort4 o; o.x=f2bf(v.x); o.y=f2bf(v.y); o.z=f2bf(v.z); o.w=f2bf(v.w);
        ((ushort4*)dst)[i] = o;
    }
}

// ---------------- Router: fp32 logits, top-2, softmax(2) ---------------------
__global__ __launch_bounds__(256) void router_kernel(
    const float* __restrict__ x, const float* __restrict__ Wr,
    const float* __restrict__ br, int* __restrict__ topIdx,
    float* __restrict__ topGate)
{
    int n = blockIdx.x * 4 + (threadIdx.x >> 6);
    int lane = threadIdx.x & 63;
    const float4* xp = (const float4*)(x + (size_t)n * D_);
    float acc[E_];
#pragma unroll
    for (int e = 0; e < E_; e++) acc[e] = 0.f;
#pragma unroll
    for (int j = 0; j < 4; j++){
        int idx = j * 64 + lane;
        float4 xv = xp[idx];
#pragma unroll
        for (int e = 0; e < E_; e++){
            float4 wv = ((const float4*)(Wr + (size_t)e * D_))[idx];
            acc[e] += xv.x*wv.x + xv.y*wv.y + xv.z*wv.z + xv.w*wv.w;
        }
    }
#pragma unroll
    for (int e = 0; e < E_; e++){
        float v = acc[e];
        for (int off = 32; off > 0; off >>= 1) v += __shfl_xor(v, off, 64);
        acc[e] = v;
    }
    if (lane == 0){
        float best = -1e30f, second = -1e30f; int bi = 0, si = 0;
#pragma unroll
        for (int e = 0; e < E_; e++){
            float v = acc[e] + br[e];
            if (v > best){ second = best; si = bi; best = v; bi = e; }
            else if (v > second){ second = v; si = e; }
        }
        float e1 = __expf(second - best);
        float denom = 1.f + e1;
        topIdx[n*2+0] = bi;  topIdx[n*2+1] = si;
        topGate[n*2+0] = 1.f/denom;  topGate[n*2+1] = e1/denom;
    }
}

__global__ __launch_bounds__(256) void hist_kernel(
    const int* __restrict__ topIdx, int* __restrict__ hdr)
{
    __shared__ int c[E_];
    int t = threadIdx.x;
    if (t < E_) c[t] = 0;
    __syncthreads();
    int e = topIdx[blockIdx.x * 256 + t];
    atomicAdd(&c[e], 1);
    __syncthreads();
    if (t < E_) hdr[256 + blockIdx.x * E_ + t] = c[t];
}

__global__ __launch_bounds__(64) void scan2_kernel(int* __restrict__ hdr)
{
    __shared__ int cnt[32 * E_];
    __shared__ int tot[E_];
    __shared__ int offs[E_ + 1];
    int t = threadIdx.x;
    for (int i = t; i < 32 * E_; i += 64) cnt[i] = hdr[256 + i];
    __syncthreads();
    if (t < E_){
        int s = 0;
        for (int b = 0; b < 32; b++) s += cnt[b * E_ + t];
        tot[t] = s;
    }
    __syncthreads();
    if (t == 0){
        int o = 0;
        for (int e = 0; e < E_; e++){ offs[e] = o; o += tot[e]; }
        offs[E_] = o;
    }
    __syncthreads();
    if (t < E_ + 1) hdr[16 + t] = offs[t];
    if (t < E_){
        int run = offs[t];
        for (int b = 0; b < 32; b++){ hdr[512 + b * E_ + t] = run; run += cnt[b * E_ + t]; }
    }
    if (t == 0){
        // 128-row tiles (fallback path)
        int tn = 0;
        for (int e = 0; e < E_; e++){
            int nt = (tot[e] + BM - 1) >> 7;
            for (int i = 0; i < nt; i++){ hdr[32 + tn] = e; hdr[112 + tn] = offs[e] + (i << 7); tn++; }
        }
        for (; tn < MAXT; tn++){ hdr[32 + tn] = -1; hdr[112 + tn] = 0; }
        // 256-row tiles (main path)
        int t2 = 0;
        for (int e = 0; e < E_; e++){
            int nt = (tot[e] + BM2 - 1) >> 8;
            for (int i = 0; i < nt; i++){ hdr[768 + t2] = e; hdr[808 + t2] = offs[e] + (i << 8); t2++; }
        }
        for (; t2 < MAXT2; t2++){ hdr[768 + t2] = -1; hdr[808 + t2] = 0; }
    }
}

__global__ __launch_bounds__(256) void pos_kernel(
    const int* __restrict__ topIdx, const float* __restrict__ topGate,
    const int* __restrict__ hdr, int* __restrict__ posOf,
    int* __restrict__ rowTok, float* __restrict__ rowGate)
{
    __shared__ int c[E_];
    int t = threadIdx.x;
    if (t < E_) c[t] = 0;
    __syncthreads();
    int slot = blockIdx.x * 256 + t;
    int e = topIdx[slot];
    int r = atomicAdd(&c[e], 1);
    int pos = hdr[512 + blockIdx.x * E_ + e] + r;
    posOf[slot] = pos;
    rowTok[pos] = slot >> 1;
    rowGate[pos] = topGate[slot];
}

__global__ __launch_bounds__(256) void copy_kernel(
    const float* __restrict__ x, const int* __restrict__ posOf,
    unsigned short* __restrict__ xg)
{
    int slot = blockIdx.x * 4 + (threadIdx.x >> 6);
    int lane = threadIdx.x & 63;
    int n = slot >> 1;
    int pos = posOf[slot];
    const float4* xp = (const float4*)(x + (size_t)n * D_);
    ushort4* op = (ushort4*)(xg + (size_t)pos * D_);
#pragma unroll
    for (int j = 0; j < 4; j++){
        float4 v = xp[j * 64 + lane];
        ushort4 o; o.x=f2bf(v.x); o.y=f2bf(v.y); o.z=f2bf(v.z); o.w=f2bf(v.w);
        op[j * 64 + lane] = o;
    }
}

// ============================================================================
// Per-K-tile body of the pipelined 256x256 GEMM. Buffers are passed as
// DISTINCT __shared__ objects with compile-time identity (the ring is fully
// unrolled at the call site). This is the discriminator vs round 2: with a
// single As[4] array + runtime kt&3 index, the compiler's LDS-DMA alias
// tracking cannot prove a ds_read of buffer q doesn't alias a pending
// global_load_lds into buffer q^1, and inserts its own vmcnt(0) before the
// ds_reads -- overriding the counted pipeline. Separate objects let alias
// analysis split them.
// Schedule per tile: {dsread A(8)+B(2) | issue A(t+3) | bar | lgkm0 | 16 MFMA
// | bar} then {dsread B(2) | issue B(t+3) | bar | lgkm0 | 16 MFMA | counted
// vmcnt | bar}. Steady state: 12 loads outstanding, vmcnt(8) retires exactly
// tile t+1. Never vmcnt(0) until the last two tiles.
// ============================================================================
__device__ __forceinline__ void gemm_tile(
    const unsigned short* AsQ, const unsigned short* BsQ,
    unsigned short* AsP, unsigned short* BsP,
    int T, int nIter, int kStart,
    const unsigned short* __restrict__ A, const unsigned short* __restrict__ Wexp,
    const u32* aOff, const u32* bOff, const u32* lOff,
    int aFrag, int bFrag, floatx4 (&acc)[8][4])
{
    // ---- phase A: ds_read A frags + B ni0/1 ; stage A(T+3) ; MFMA ni0/1
    short8 af[8];
#pragma unroll
    for (int mi = 0; mi < 8; mi++)
        af[mi] = *(const short8*)(AsQ + aFrag + mi * 512);
    short8 bf0 = *(const short8*)(BsQ + bFrag);
    short8 bf1 = *(const short8*)(BsQ + bFrag + 512);
    if (T + 3 < nIter){
        u32 k0 = (u32)(kStart + (T + 3) * BK2);
        async16(A + aOff[0] + k0, (char*)AsP + lOff[0]);
        async16(A + aOff[1] + k0, (char*)AsP + lOff[1]);
    }
    sb();
    __builtin_amdgcn_s_barrier();
    asm volatile("s_waitcnt lgkmcnt(0)");
    sb();
    __builtin_amdgcn_s_setprio(1);
#pragma unroll
    for (int mi = 0; mi < 8; mi++)
        acc[mi][0] = __builtin_amdgcn_mfma_f32_16x16x32_bf16(af[mi], bf0, acc[mi][0], 0, 0, 0);
#pragma unroll
    for (int mi = 0; mi < 8; mi++)
        acc[mi][1] = __builtin_amdgcn_mfma_f32_16x16x32_bf16(af[mi], bf1, acc[mi][1], 0, 0, 0);
    __builtin_amdgcn_s_setprio(0);
    sb();
    __builtin_amdgcn_s_barrier();
    sb();

    // ---- phase B: ds_read B ni2/3 ; stage B(T+3) ; MFMA ni2/3 ; counted wait
    short8 bf2 = *(const short8*)(BsQ + bFrag + 1024);
    short8 bf3 = *(const short8*)(BsQ + bFrag + 1536);
    if (T + 3 < nIter){
        u32 k0 = (u32)(kStart + (T + 3) * BK2);
        async16(Wexp + bOff[0] + k0, (char*)BsP + lOff[0]);
        async16(Wexp + bOff[1] + k0, (char*)BsP + lOff[1]);
    }
    sb();
    __builtin_amdgcn_s_barrier();
    asm volatile("s_waitcnt lgkmcnt(0)");
    sb();
    __builtin_amdgcn_s_setprio(1);
#pragma unroll
    for (int mi = 0; mi < 8; mi++)
        acc[mi][2] = __builtin_amdgcn_mfma_f32_16x16x32_bf16(af[mi], bf2, acc[mi][2], 0, 0, 0);
#pragma unroll
    for (int mi = 0; mi < 8; mi++)
        acc[mi][3] = __builtin_amdgcn_mfma_f32_16x16x32_bf16(af[mi], bf3, acc[mi][3], 0, 0, 0);
    __builtin_amdgcn_s_setprio(0);
    sb();
    // per-wave counted retire: guarantee THIS wave's tile T+1 loads landed,
    // then barrier joins all waves -> tile T+1 globally ready.
    if (T + 4 <= nIter)      asm volatile("s_waitcnt vmcnt(8)");
    else if (T + 3 == nIter) asm volatile("s_waitcnt vmcnt(4)");
    else if (T + 2 == nIter) asm volatile("s_waitcnt vmcnt(0)");
    sb();
    __builtin_amdgcn_s_barrier();
    sb();
}

// MODE 1: hout = relu(A@W^T+b) bf16.  MODE 2: out[tok] += gate*(A@W^T+b).
template<int MODE>
__global__ __launch_bounds__(512, 2) void moe_gemm2(
    const unsigned short* __restrict__ A, int Ktot,
    const unsigned short* __restrict__ Wbase, size_t wStride,
    const float* __restrict__ biasBase, int biasStride,
    const int* __restrict__ hdr,
    const int* __restrict__ rowTok, const float* __restrict__ rowGate,
    unsigned short* __restrict__ hout, float* __restrict__ out)
{
    // bijective XCD-aware remap (m204)
    int nwg  = gridDim.x * gridDim.y * gridDim.z;
    int orig = (blockIdx.z * gridDim.y + blockIdx.y) * gridDim.x + blockIdx.x;
    int xcd = orig & 7, loc = orig >> 3;
    int q8 = nwg >> 3, r8 = nwg & 7;
    int wgid = (xcd < r8 ? xcd * (q8 + 1) : r8 * (q8 + 1) + (xcd - r8) * q8) + loc;
    int bx = wgid % gridDim.x;
    int tt = wgid / gridDim.x;
    int by = tt % gridDim.y;
    int bz = tt / gridDim.y;

    int e = hdr[768 + bx];
    if (e < 0) return;
    int rowBase = hdr[808 + bx];
    int validRows = hdr[16 + e + 1] - rowBase;

    int kChunk = Ktot / gridDim.z;
    int kStart = bz * kChunk;
    int nIter  = kChunk / BK2;           // = 32 for both GEMMs (nIter % 4 == 0)

    // 8 DISTINCT shared objects: ring-of-4 double operand buffers, 128 KiB.
    __shared__ __align__(16) unsigned short As0[BM2 * BK2];
    __shared__ __align__(16) unsigned short As1[BM2 * BK2];
    __shared__ __align__(16) unsigned short As2[BM2 * BK2];
    __shared__ __align__(16) unsigned short As3[BM2 * BK2];
    __shared__ __align__(16) unsigned short Bs0[BN2 * BK2];
    __shared__ __align__(16) unsigned short Bs1[BN2 * BK2];
    __shared__ __align__(16) unsigned short Bs2[BN2 * BK2];
    __shared__ __align__(16) unsigned short Bs3[BN2 * BK2];

    const int tid  = threadIdx.x;
    const int lane = tid & 63, wave = tid >> 6;
    const int wm = wave >> 2, wn = wave & 3;     // 2 x 4 wave grid
    const int l16 = lane & 15, quad = lane >> 4;

    const unsigned short* Wexp = Wbase + (size_t)e * wStride + (size_t)(by * BN2) * Ktot;

    // staging descriptors: 2 x 16B granules per thread per operand per K-tile
    u32 aOff[2], bOff[2], lOff[2];
#pragma unroll
    for (int i = 0; i < 2; i++){
        int s = i * 512 + tid;
        int rr = s >> 2, gst = s & 3;
        int gsrc = gst ^ ((rr >> 1) & 3);       // pre-swizzled source granule
        int ar = rowBase + rr; ar = ar < (NSLOT - 1) ? ar : (NSLOT - 1);
        aOff[i] = (u32)ar * (u32)Ktot + (u32)(gsrc * 8);
        bOff[i] = (u32)rr * (u32)Ktot + (u32)(gsrc * 8);
        lOff[i] = (u32)(s * 16);
    }

    floatx4 acc[8][4];
#pragma unroll
    for (int mi = 0; mi < 8; mi++)
#pragma unroll
        for (int ni = 0; ni < 4; ni++)
            acc[mi][ni] = (floatx4){0.f, 0.f, 0.f, 0.f};

    const int pg    = quad ^ ((l16 >> 1) & 3);             // swizzled read granule
    const int aFrag = (wm * 128 + l16) * 32 + pg * 8;      // ushort index
    const int bFrag = (wn * 64  + l16) * 32 + pg * 8;

    // prologue: tiles 0,1,2 -> buffers 0,1,2 (12 loads; order A(t),B(t))
    {
        u32 k0 = (u32)kStart;
        async16(A    + aOff[0] + k0, (char*)As0 + lOff[0]);
        async16(A    + aOff[1] + k0, (char*)As0 + lOff[1]);
        async16(Wexp + bOff[0] + k0, (char*)Bs0 + lOff[0]);
        async16(Wexp + bOff[1] + k0, (char*)Bs0 + lOff[1]);
        u32 k1 = k0 + BK2;
        async16(A    + aOff[0] + k1, (char*)As1 + lOff[0]);
        async16(A    + aOff[1] + k1, (char*)As1 + lOff[1]);
        async16(Wexp + bOff[0] + k1, (char*)Bs1 + lOff[0]);
        async16(Wexp + bOff[1] + k1, (char*)Bs1 + lOff[1]);
        u32 k2 = k0 + 2 * BK2;
        async16(A    + aOff[0] + k2, (char*)As2 + lOff[0]);
        async16(A    + aOff[1] + k2, (char*)As2 + lOff[1]);
        async16(Wexp + bOff[0] + k2, (char*)Bs2 + lOff[0]);
        async16(Wexp + bOff[1] + k2, (char*)Bs2 + lOff[1]);
    }
    sb();
    asm volatile("s_waitcnt vmcnt(8)");   // tile 0 landed; tiles 1,2 in flight
    sb();
    __builtin_amdgcn_s_barrier();
    sb();

    // fully unrolled ring-of-4 (nIter == 32, multiple of 4)
    for (int t = 0; t < nIter; t += 4){
        gemm_tile(As0, Bs0, As3, Bs3, t,     nIter, kStart, A, Wexp, aOff, bOff, lOff, aFrag, bFrag, acc);
        gemm_tile(As1, Bs1, As0, Bs0, t + 1, nIter, kStart, A, Wexp, aOff, bOff, lOff, aFrag, bFrag, acc);
        gemm_tile(As2, Bs2, As1, Bs1, t + 2, nIter, kStart, A, Wexp, aOff, bOff, lOff, aFrag, bFrag, acc);
        gemm_tile(As3, Bs3, As2, Bs2, t + 3, nIter, kStart, A, Wexp, aOff, bOff, lOff, aFrag, bFrag, acc);
    }

    // ---- epilogue
    bool addB = (MODE == 1) || (bz == 0);
    const float* biasE = biasBase + (size_t)e * biasStride + by * BN2;
    float biasv[4];
#pragma unroll
    for (int ni = 0; ni < 4; ni++)
        biasv[ni] = addB ? biasE[wn * 64 + ni * 16 + l16] : 0.f;

#pragma unroll
    for (int mi = 0; mi < 8; mi++){
#pragma unroll
        for (int r2 = 0; r2 < 4; r2++){
            int rl = wm * 128 + mi * 16 + quad * 4 + r2;
            if (rl >= validRows) continue;
            int grow = rowBase + rl;
            int tok = 0; float gate = 0.f;
            if (MODE == 2){ tok = rowTok[grow]; gate = rowGate[grow]; }
#pragma unroll
            for (int ni = 0; ni < 4; ni++){
                int gcol = by * BN2 + wn * 64 + ni * 16 + l16;
                float v = acc[mi][ni][r2] + biasv[ni];
                if (MODE == 1){
                    v = v > 0.f ? v : 0.f;
                    hout[(size_t)grow * H_ + gcol] = f2bf(v);
                } else {
                    atomicAdd(out + (size_t)tok * D_ + gcol, gate * v);
                }
            }
        }
    }
}

// ---------------- legacy 128^2 grouped GEMM (fp32-weight fallback only) ------
template<int MODE, bool BF16B>
__global__ __launch_bounds__(256) void moe_gemm(
    const unsigned short* __restrict__ A, int Ktot,
    const void* __restrict__ Wbase, size_t wStride,
    const float* __restrict__ biasBase, int biasStride,
    const int* __restrict__ hdr,
    const int* __restrict__ rowTok, const float* __restrict__ rowGate,
    unsigned short* __restrict__ hout, float* __restrict__ out)
{
    int gid = blockIdx.y * gridDim.x + blockIdx.x;
    int per = gridDim.x * 8;
    int g = gid / per, rr = gid % per;
    int by = g * 8 + (rr & 7);
    int bx = rr >> 3;

    int e = hdr[32 + bx];
    if (e < 0) return;
    int rowBase = hdr[112 + bx];
    int validRows = hdr[16 + e + 1] - rowBase;

    int kChunk = Ktot / gridDim.z;
    int kStart = blockIdx.z * kChunk;

    __shared__ __align__(16) unsigned short As[2][BM * BK];
    __shared__ __align__(16) unsigned short BsH[BF16B ? 2 * BN * BK : 1];
    __shared__ __align__(16) float BsF[BF16B ? 1 : BN * BK];

    const float* biasE = biasBase + (size_t)e * biasStride + by * BN;

    const int tid  = threadIdx.x;
    const int lane = tid & 63, wave = tid >> 6;
    const int wm = wave & 1, wn = wave >> 1;
    const int l16 = lane & 15, quad = lane >> 4;

    floatx4 acc[4][4];
#pragma unroll
    for (int mi = 0; mi < 4; mi++)
#pragma unroll
        for (int ni = 0; ni < 4; ni++)
            acc[mi][ni] = (floatx4){0.f,0.f,0.f,0.f};

    if (BF16B){
        const unsigned short* Wexp = (const unsigned short*)Wbase
            + (size_t)e * wStride + (size_t)(by * BN) * Ktot;
        size_t aOff[2], bOff[2];
        int    lOff[2];
#pragma unroll
        for (int i = 0; i < 2; i++){
            int s = i * 256 + tid;
            int r = s >> 2, gst = s & 3;
            int gsrc = gst ^ ((r >> 1) & 3);
            int ar = rowBase + r;
            ar = ar < (NSLOT - 1) ? ar : (NSLOT - 1);
            aOff[i] = (size_t)ar * Ktot + gsrc * 8;
            bOff[i] = (size_t)r  * Ktot + gsrc * 8;
            lOff[i] = s * 16;
        }
#pragma unroll
        for (int i = 0; i < 2; i++){
            async16(A    + aOff[i] + kStart, (char*)As[0]  + lOff[i]);
            async16(Wexp + bOff[i] + kStart, (char*)BsH    + lOff[i]);
        }
        int nIter = kChunk / BK;
        for (int it = 0; it < nIter; it++){
            __syncthreads();
            int p = it & 1;
            if (it + 1 < nIter){
                int kn = kStart + (it + 1) * BK;
#pragma unroll
                for (int i = 0; i < 2; i++){
                    async16(A    + aOff[i] + kn, (char*)As[p ^ 1] + lOff[i]);
                    async16(Wexp + bOff[i] + kn, (char*)BsH + (p ^ 1) * (BN * BK * 2) + lOff[i]);
                }
            }
            short8 af[4], bfr[4];
#pragma unroll
            for (int mi = 0; mi < 4; mi++){
                int r = wm*64 + mi*16 + l16;
                int gq = quad ^ ((r >> 1) & 3);
                af[mi] = *(const short8*)(As[p] + r * BK + gq * 8);
            }
#pragma unroll
            for (int ni = 0; ni < 4; ni++){
                int n = wn*64 + ni*16 + l16;
                int gq = quad ^ ((n >> 1) & 3);
                bfr[ni] = *(const short8*)(BsH + p * (BN * BK) + n * BK + gq * 8);
            }
#pragma unroll
            for (int mi = 0; mi < 4; mi++)
#pragma unroll
                for (int ni = 0; ni < 4; ni++)
                    acc[mi][ni] = __builtin_amdgcn_mfma_f32_16x16x32_bf16(
                        af[mi], bfr[ni], acc[mi][ni], 0, 0, 0);
        }
    } else {
        const float* Wexp = (const float*)Wbase
            + (size_t)e * wStride + (size_t)(by * BN) * Ktot;
        int aS[2], aRow[2], aCol[2];
#pragma unroll
        for (int i = 0; i < 2; i++){
            int s = i * 256 + tid;
            aS[i] = s;
            int r = rowBase + (s >> 2);
            aRow[i] = r < (NSLOT - 1) ? r : (NSLOT - 1);
            aCol[i] = (s & 3) * 8;
        }
        int bS[4], bRow[4], bCol[4];
#pragma unroll
        for (int i = 0; i < 4; i++){
            int s = i * 256 + tid;
            bS[i] = s;
            int r = s >> 3, c = s & 7;
            bRow[i] = r;
            bCol[i] = (c ^ (r & 7)) * 4;
        }
        for (int k0 = kStart; k0 < kStart + kChunk; k0 += BK){
#pragma unroll
            for (int i = 0; i < 2; i++)
                async16(A + (size_t)aRow[i] * Ktot + k0 + aCol[i], (char*)As[0] + aS[i] * 16);
#pragma unroll
            for (int i = 0; i < 4; i++)
                async16(Wexp + (size_t)bRow[i] * Ktot + k0 + bCol[i], (char*)BsF + bS[i] * 16);
            __syncthreads();
            short8 af[4], bfr[4];
#pragma unroll
            for (int mi = 0; mi < 4; mi++)
                af[mi] = *(const short8*)(As[0] + (wm*64 + mi*16 + l16) * BK + quad * 8);
#pragma unroll
            for (int ni = 0; ni < 4; ni++){
                int n = wn*64 + ni*16 + l16;
                int g0 = (2*quad)     ^ (n & 7);
                int g1 = (2*quad + 1) ^ (n & 7);
                float4 u0 = *(const float4*)(BsF + n * BK + g0 * 4);
                float4 u1 = *(const float4*)(BsF + n * BK + g1 * 4);
                union { short8 s; __hip_bfloat162 h[4]; } u;
                u.h[0] = __float22bfloat162_rn(make_float2(u0.x, u0.y));
                u.h[1] = __float22bfloat162_rn(make_float2(u0.z, u0.w));
                u.h[2] = __float22bfloat162_rn(make_float2(u1.x, u1.y));
                u.h[3] = __float22bfloat162_rn(make_float2(u1.z, u1.w));
                bfr[ni] = u.s;
            }
#pragma unroll
            for (int mi = 0; mi < 4; mi++)
#pragma unroll
                for (int ni = 0; ni < 4; ni++)
                    acc[mi][ni] = __builtin_amdgcn_mfma_f32_16x16x32_bf16(
                        af[mi], bfr[ni], acc[mi][ni], 0, 0, 0);
            __syncthreads();
        }
    }

    bool addB = (MODE == 1) || (blockIdx.z == 0);
#pragma unroll
    for (int mi = 0; mi < 4; mi++){
#pragma unroll
        for (int r = 0; r < 4; r++){
            int rl = wm*64 + mi*16 + quad*4 + r;
            if (rl >= validRows) continue;
            int grow = rowBase + rl;
            int   tok  = 0;
            float gate = 0.f;
            if (MODE == 2){ tok = rowTok[grow]; gate = rowGate[grow]; }
#pragma unroll
            for (int ni = 0; ni < 4; ni++){
                int lcol = wn*64 + ni*16 + l16;
                int gcol = by * BN + lcol;
                float v = acc[mi][ni][r] + (addB ? biasE[lcol] : 0.f);
                if (MODE == 1){
                    v = v > 0.f ? v : 0.f;
                    hout[(size_t)grow * H_ + gcol] = f2bf(v);
                } else {
                    atomicAdd(out + (size_t)tok * D_ + gcol, gate * v);
                }
            }
        }
    }
}

// ---------------- launch -----------------------------------------------------
extern "C" void kernel_launch(void* const* d_in, const int* in_sizes, int n_in,
                              void* d_out, int out_size, void* d_ws, size_t ws_size,
                              hipStream_t stream)
{
    (void)in_sizes; (void)n_in;
    const float* x  = (const float*)d_in[0];
    const float* Wr = (const float*)d_in[1];
    const float* br = (const float*)d_in[2];
    const float* W1 = (const float*)d_in[3];
    const float* b1 = (const float*)d_in[4];
    const float* W2 = (const float*)d_in[5];
    const float* b2 = (const float*)d_in[6];
    float* out = (float*)d_out;

    char* ws = (char*)d_ws;
    int*   hdr     = (int*)ws;
    int*   topIdx  = (int*)  (ws + 4096);
    float* topGate = (float*)(ws + 36864);
    int*   posOf   = (int*)  (ws + 69632);
    int*   rowTok  = (int*)  (ws + 102400);
    float* rowGate = (float*)(ws + 135168);
    unsigned short* xg   = (unsigned short*)(ws + 262144);     // 16.78 MB
    unsigned short* hbuf = (unsigned short*)(ws + 17039360);   // 67.1 MB
    unsigned short* w1b  = (unsigned short*)(ws + 84148224);   // 67.1 MB
    unsigned short* w2b  = (unsigned short*)(ws + 151257088);  // 67.1 MB -> ends 218365952
    const bool full = ws_size >= 218365952ull;

    hipMemsetAsync(d_out, 0, (size_t)out_size * sizeof(float), stream);

    router_kernel<<<N_TOK/4, 256, 0, stream>>>(x, Wr, br, topIdx, topGate);
    hist_kernel<<<32, 256, 0, stream>>>(topIdx, hdr);
    scan2_kernel<<<1, 64, 0, stream>>>(hdr);
    pos_kernel<<<32, 256, 0, stream>>>(topIdx, topGate, hdr, posOf, rowTok, rowGate);
    copy_kernel<<<NSLOT/4, 256, 0, stream>>>(x, posOf, xg);

    if (full){
        cvt_kernel<<<2048, 256, 0, stream>>>(W1, w1b, (E_*H_*D_)/4);
        cvt_kernel<<<2048, 256, 0, stream>>>(W2, w2b, (E_*D_*H_)/4);
        moe_gemm2<1><<<dim3(MAXT2, H_/BN2, 1), 512, 0, stream>>>(
            xg, D_, w1b, (size_t)H_ * D_, b1, H_, hdr, rowTok, rowGate, hbuf, nullptr);
        moe_gemm2<2><<<dim3(MAXT2, D_/BN2, 4), 512, 0, stream>>>(
            hbuf, H_, w2b, (size_t)D_ * H_, b2, D_, hdr, rowTok, rowGate, nullptr, out);
    } else {
        moe_gemm<1,false><<<dim3(MAXT, H_/BN, 1), 256, 0, stream>>>(
            xg, D_, W1, (size_t)H_ * D_, b1, H_, hdr, rowTok, rowGate, hbuf, nullptr);
        moe_gemm<2,false><<<dim3(MAXT, D_/BN, 2), 256, 0, stream>>>(
            hbuf, H_, W2, (size_t)D_ * H_, b2, D_, hdr, rowTok, rowGate, nullptr, out);
    }
}

// Round 6
// 632.486 us; speedup vs baseline: 3.9024x; 1.0204x over previous
//
#include <hip/hip_runtime.h>
#include <hip/hip_bf16.h>
#include <stdint.h>

#define N_TOK 4096
#define D_ 1024
#define H_ 4096
#define E_ 8
#define NSLOT (N_TOK*2)
#define BM 128
#define BN 128
#define BK 32
#define MAXT 72

typedef __attribute__((ext_vector_type(8))) short short8;
typedef __attribute__((ext_vector_type(4))) float floatx4;
typedef unsigned int u32;

__device__ __forceinline__ unsigned short f2bf(float f){
    union { float f; unsigned int u; } c; c.f = f;
    unsigned int u = c.u;
    unsigned int r = (u + 0x7fffu + ((u >> 16) & 1u)) >> 16;  // RNE
    return (unsigned short)r;
}

__device__ __forceinline__ void async16(const void* g, void* l){
    __builtin_amdgcn_global_load_lds(
        (const __attribute__((address_space(1))) u32*)g,
        (__attribute__((address_space(3))) u32*)l, 16, 0, 0);
}

// ---------------- Router: fp32 logits, top-2, softmax(2) ---------------------
__global__ __launch_bounds__(256) void router_kernel(
    const float* __restrict__ x, const float* __restrict__ Wr,
    const float* __restrict__ br, int* __restrict__ topIdx,
    float* __restrict__ topGate)
{
    int n = blockIdx.x * 4 + (threadIdx.x >> 6);
    int lane = threadIdx.x & 63;
    const float4* xp = (const float4*)(x + (size_t)n * D_);
    float acc[E_];
#pragma unroll
    for (int e = 0; e < E_; e++) acc[e] = 0.f;
#pragma unroll
    for (int j = 0; j < 4; j++){
        int idx = j * 64 + lane;
        float4 xv = xp[idx];
#pragma unroll
        for (int e = 0; e < E_; e++){
            float4 wv = ((const float4*)(Wr + (size_t)e * D_))[idx];
            acc[e] += xv.x*wv.x + xv.y*wv.y + xv.z*wv.z + xv.w*wv.w;
        }
    }
#pragma unroll
    for (int e = 0; e < E_; e++){
        float v = acc[e];
        for (int off = 32; off > 0; off >>= 1) v += __shfl_xor(v, off, 64);
        acc[e] = v;
    }
    if (lane == 0){
        float best = -1e30f, second = -1e30f; int bi = 0, si = 0;
#pragma unroll
        for (int e = 0; e < E_; e++){
            float v = acc[e] + br[e];
            if (v > best){ second = best; si = bi; best = v; bi = e; }
            else if (v > second){ second = v; si = e; }
        }
        float e1 = __expf(second - best);
        float denom = 1.f + e1;
        topIdx[n*2+0] = bi;  topIdx[n*2+1] = si;
        topGate[n*2+0] = 1.f/denom;  topGate[n*2+1] = e1/denom;
    }
}

__global__ __launch_bounds__(256) void hist_kernel(
    const int* __restrict__ topIdx, int* __restrict__ hdr)
{
    __shared__ int c[E_];
    int t = threadIdx.x;
    if (t < E_) c[t] = 0;
    __syncthreads();
    int e = topIdx[blockIdx.x * 256 + t];
    atomicAdd(&c[e], 1);
    __syncthreads();
    if (t < E_) hdr[256 + blockIdx.x * E_ + t] = c[t];
}

__global__ __launch_bounds__(64) void scan2_kernel(int* __restrict__ hdr)
{
    __shared__ int cnt[32 * E_];
    __shared__ int tot[E_];
    __shared__ int offs[E_ + 1];
    int t = threadIdx.x;
    for (int i = t; i < 32 * E_; i += 64) cnt[i] = hdr[256 + i];
    __syncthreads();
    if (t < E_){
        int s = 0;
        for (int b = 0; b < 32; b++) s += cnt[b * E_ + t];
        tot[t] = s;
    }
    __syncthreads();
    if (t == 0){
        int o = 0;
        for (int e = 0; e < E_; e++){ offs[e] = o; o += tot[e]; }
        offs[E_] = o;
    }
    __syncthreads();
    if (t < E_ + 1) hdr[16 + t] = offs[t];
    if (t < E_){
        int run = offs[t];
        for (int b = 0; b < 32; b++){ hdr[512 + b * E_ + t] = run; run += cnt[b * E_ + t]; }
    }
    if (t == 0){
        int tn = 0;
        for (int e = 0; e < E_; e++){
            int nt = (tot[e] + BM - 1) >> 7;
            for (int i = 0; i < nt; i++){ hdr[32 + tn] = e; hdr[112 + tn] = offs[e] + (i << 7); tn++; }
        }
        for (; tn < MAXT; tn++){ hdr[32 + tn] = -1; hdr[112 + tn] = 0; }
    }
}

__global__ __launch_bounds__(256) void pos_kernel(
    const int* __restrict__ topIdx, const float* __restrict__ topGate,
    const int* __restrict__ hdr, int* __restrict__ posOf,
    int* __restrict__ rowTok, float* __restrict__ rowGate)
{
    __shared__ int c[E_];
    int t = threadIdx.x;
    if (t < E_) c[t] = 0;
    __syncthreads();
    int slot = blockIdx.x * 256 + t;
    int e = topIdx[slot];
    int r = atomicAdd(&c[e], 1);
    int pos = hdr[512 + blockIdx.x * E_ + e] + r;
    posOf[slot] = pos;
    rowTok[pos] = slot >> 1;
    rowGate[pos] = topGate[slot];
}

__global__ __launch_bounds__(256) void copy_kernel(
    const float* __restrict__ x, const int* __restrict__ posOf,
    unsigned short* __restrict__ xg)
{
    int slot = blockIdx.x * 4 + (threadIdx.x >> 6);
    int lane = threadIdx.x & 63;
    int n = slot >> 1;
    int pos = posOf[slot];
    const float4* xp = (const float4*)(x + (size_t)n * D_);
    ushort4* op = (ushort4*)(xg + (size_t)pos * D_);
#pragma unroll
    for (int j = 0; j < 4; j++){
        float4 v = xp[j * 64 + lane];
        ushort4 o; o.x=f2bf(v.x); o.y=f2bf(v.y); o.z=f2bf(v.z); o.w=f2bf(v.w);
        op[j * 64 + lane] = o;
    }
}

// ============================================================================
// 128x128 grouped GEMM, bf16 A (staged) x fp32 W (staged, converted to bf16
// at ds_read). Round-0 structure (fastest measured: 195 us, ~3 blocks/CU,
// double-buffered, 1 barrier/iter) but reading W in fp32 DIRECTLY -- this
// removes the two cvt_kernel passes (~150 us of pure HBM traffic) from the
// critical path. The GEMM runs at only ~20-25% of HBM, so the 2x B-operand
// staging bytes fit in existing bandwidth headroom.
//   LDS: As 2x8 KB bf16 + BsF 2x16 KB fp32 = 48 KB -> 3 blocks/CU.
//   A swizzle: store granule g^((r>>1)&3), read quad^((r>>1)&3)  [0 conflicts]
//   B swizzle: store granule c^(r&7),     read (2q+j)^(n&7)      [2-way max]
//   fp32->bf16 at read: 2x float4 + __float22bfloat162_rn x4 (legacy-verified)
// MODE 1: hout = relu(A@W1^T+b1) bf16.  MODE 2: out[tok] += gate*(A@W2^T+b2).
// ============================================================================
template<int MODE>
__global__ __launch_bounds__(256) void moe_gemm(
    const unsigned short* __restrict__ A, int Ktot,
    const float* __restrict__ Wbase, size_t wStride,
    const float* __restrict__ biasBase, int biasStride,
    const int* __restrict__ hdr,
    const int* __restrict__ rowTok, const float* __restrict__ rowGate,
    unsigned short* __restrict__ hout, float* __restrict__ out)
{
    // dispatch-order swizzle: by fast within groups of 8 (A + W-slice locality)
    int gid = blockIdx.y * gridDim.x + blockIdx.x;
    int per = gridDim.x * 8;
    int g = gid / per, rr = gid % per;
    int by = g * 8 + (rr & 7);
    int bx = rr >> 3;

    int e = hdr[32 + bx];
    if (e < 0) return;
    int rowBase = hdr[112 + bx];
    int validRows = hdr[16 + e + 1] - rowBase;

    int kChunk = Ktot / gridDim.z;
    int kStart = blockIdx.z * kChunk;
    int nIter  = kChunk / BK;

    __shared__ __align__(16) unsigned short As[2][BM * BK];   // 2 x 8 KB
    __shared__ __align__(16) float          BsF[2][BN * BK];  // 2 x 16 KB

    const float* biasE = biasBase + (size_t)e * biasStride + by * BN;

    const int tid  = threadIdx.x;
    const int lane = tid & 63, wave = tid >> 6;
    const int wm = wave & 1, wn = wave >> 1;
    const int l16 = lane & 15, quad = lane >> 4;

    const float* Wexp = Wbase + (size_t)e * wStride + (size_t)(by * BN) * Ktot;

    // A staging descriptors: 2 x 16B bf16 granules per thread per K-tile
    size_t aOff[2]; int aS[2];
#pragma unroll
    for (int i = 0; i < 2; i++){
        int s = i * 256 + tid;
        int r = s >> 2, gst = s & 3;
        int gsrc = gst ^ ((r >> 1) & 3);
        int ar = rowBase + r;
        ar = ar < (NSLOT - 1) ? ar : (NSLOT - 1);   // clamp; junk masked later
        aOff[i] = (size_t)ar * Ktot + gsrc * 8;
        aS[i] = s * 16;
    }
    // B staging descriptors: 4 x 16B fp32 granules per thread per K-tile
    size_t bOff[4]; int bS[4];
#pragma unroll
    for (int i = 0; i < 4; i++){
        int s = i * 256 + tid;
        int r = s >> 3, c = s & 7;
        bOff[i] = (size_t)r * Ktot + (size_t)((c ^ (r & 7)) * 4);
        bS[i] = s * 16;
    }

    floatx4 acc[4][4];
#pragma unroll
    for (int mi = 0; mi < 4; mi++)
#pragma unroll
        for (int ni = 0; ni < 4; ni++)
            acc[mi][ni] = (floatx4){0.f,0.f,0.f,0.f};

    // prologue: tile 0 -> buffer 0
#pragma unroll
    for (int i = 0; i < 2; i++)
        async16(A + aOff[i] + kStart, (char*)As[0] + aS[i]);
#pragma unroll
    for (int i = 0; i < 4; i++)
        async16(Wexp + bOff[i] + kStart, (char*)BsF[0] + bS[i]);

    for (int it = 0; it < nIter; it++){
        __syncthreads();                       // buffer p ready (vmcnt drain)
        int p = it & 1;
        if (it + 1 < nIter){
            int kn = kStart + (it + 1) * BK;
#pragma unroll
            for (int i = 0; i < 2; i++)
                async16(A + aOff[i] + kn, (char*)As[p ^ 1] + aS[i]);
#pragma unroll
            for (int i = 0; i < 4; i++)
                async16(Wexp + bOff[i] + kn, (char*)BsF[p ^ 1] + bS[i]);
        }
        short8 af[4], bfr[4];
#pragma unroll
        for (int mi = 0; mi < 4; mi++){
            int r = wm*64 + mi*16 + l16;
            int gq = quad ^ ((r >> 1) & 3);
            af[mi] = *(const short8*)(As[p] + r * BK + gq * 8);
        }
#pragma unroll
        for (int ni = 0; ni < 4; ni++){
            int n = wn*64 + ni*16 + l16;
            int g0 = (2*quad)     ^ (n & 7);
            int g1 = (2*quad + 1) ^ (n & 7);
            float4 u0 = *(const float4*)(BsF[p] + n * BK + g0 * 4);
            float4 u1 = *(const float4*)(BsF[p] + n * BK + g1 * 4);
            union { short8 s; __hip_bfloat162 h[4]; } u;
            u.h[0] = __float22bfloat162_rn(make_float2(u0.x, u0.y));
            u.h[1] = __float22bfloat162_rn(make_float2(u0.z, u0.w));
            u.h[2] = __float22bfloat162_rn(make_float2(u1.x, u1.y));
            u.h[3] = __float22bfloat162_rn(make_float2(u1.z, u1.w));
            bfr[ni] = u.s;
        }
        __builtin_amdgcn_s_setprio(1);
#pragma unroll
        for (int mi = 0; mi < 4; mi++)
#pragma unroll
            for (int ni = 0; ni < 4; ni++)
                acc[mi][ni] = __builtin_amdgcn_mfma_f32_16x16x32_bf16(
                    af[mi], bfr[ni], acc[mi][ni], 0, 0, 0);
        __builtin_amdgcn_s_setprio(0);
    }

    bool addB = (MODE == 1) || (blockIdx.z == 0);
#pragma unroll
    for (int mi = 0; mi < 4; mi++){
#pragma unroll
        for (int r = 0; r < 4; r++){
            int rl = wm*64 + mi*16 + quad*4 + r;
            if (rl >= validRows) continue;
            int grow = rowBase + rl;
            int   tok  = 0;
            float gate = 0.f;
            if (MODE == 2){ tok = rowTok[grow]; gate = rowGate[grow]; }
#pragma unroll
            for (int ni = 0; ni < 4; ni++){
                int lcol = wn*64 + ni*16 + l16;
                int gcol = by * BN + lcol;
                float v = acc[mi][ni][r] + (addB ? biasE[lcol] : 0.f);
                if (MODE == 1){
                    v = v > 0.f ? v : 0.f;
                    hout[(size_t)grow * H_ + gcol] = f2bf(v);
                } else {
                    atomicAdd(out + (size_t)tok * D_ + gcol, gate * v);
                }
            }
        }
    }
}

// ---------------- launch -----------------------------------------------------
extern "C" void kernel_launch(void* const* d_in, const int* in_sizes, int n_in,
                              void* d_out, int out_size, void* d_ws, size_t ws_size,
                              hipStream_t stream)
{
    (void)in_sizes; (void)n_in; (void)ws_size;
    const float* x  = (const float*)d_in[0];
    const float* Wr = (const float*)d_in[1];
    const float* br = (const float*)d_in[2];
    const float* W1 = (const float*)d_in[3];
    const float* b1 = (const float*)d_in[4];
    const float* W2 = (const float*)d_in[5];
    const float* b2 = (const float*)d_in[6];
    float* out = (float*)d_out;

    char* ws = (char*)d_ws;
    int*   hdr     = (int*)ws;
    int*   topIdx  = (int*)  (ws + 4096);
    float* topGate = (float*)(ws + 36864);
    int*   posOf   = (int*)  (ws + 69632);
    int*   rowTok  = (int*)  (ws + 102400);
    float* rowGate = (float*)(ws + 135168);
    unsigned short* xg   = (unsigned short*)(ws + 262144);     // 16.78 MB
    unsigned short* hbuf = (unsigned short*)(ws + 17039360);   // 67.1 MB -> ends 84.1 MB

    hipMemsetAsync(d_out, 0, (size_t)out_size * sizeof(float), stream);

    router_kernel<<<N_TOK/4, 256, 0, stream>>>(x, Wr, br, topIdx, topGate);
    hist_kernel<<<32, 256, 0, stream>>>(topIdx, hdr);
    scan2_kernel<<<1, 64, 0, stream>>>(hdr);
    pos_kernel<<<32, 256, 0, stream>>>(topIdx, topGate, hdr, posOf, rowTok, rowGate);
    copy_kernel<<<NSLOT/4, 256, 0, stream>>>(x, posOf, xg);

    // fp32 weights consumed directly (no cvt pass)
    moe_gemm<1><<<dim3(MAXT, H_/BN, 1), 256, 0, stream>>>(
        xg, D_, W1, (size_t)H_ * D_, b1, H_, hdr, rowTok, rowGate, hbuf, nullptr);
    moe_gemm<2><<<dim3(MAXT, D_/BN, 2), 256, 0, stream>>>(
        hbuf, H_, W2, (size_t)D_ * H_, b2, D_, hdr, rowTok, rowGate, nullptr, out);
}

// Round 7
// 627.367 us; speedup vs baseline: 3.9343x; 1.0082x over previous
//
#include <hip/hip_runtime.h>
#include <hip/hip_bf16.h>
#include <stdint.h>

#define N_TOK 4096
#define D_ 1024
#define H_ 4096
#define E_ 8
#define NSLOT (N_TOK*2)
#define BM 128
#define BN 128
#define BK 32
#define MAXT 72

typedef __attribute__((ext_vector_type(8))) short short8;
typedef __attribute__((ext_vector_type(4))) float floatx4;
typedef unsigned int u32;

__device__ __forceinline__ unsigned short f2bf(float f){
    union { float f; unsigned int u; } c; c.f = f;
    unsigned int u = c.u;
    unsigned int r = (u + 0x7fffu + ((u >> 16) & 1u)) >> 16;  // RNE
    return (unsigned short)r;
}

__device__ __forceinline__ void async16(const void* g, void* l){
    __builtin_amdgcn_global_load_lds(
        (const __attribute__((address_space(1))) u32*)g,
        (__attribute__((address_space(3))) u32*)l, 16, 0, 0);
}

// ---------------- Router: fp32 logits, top-2, softmax(2) ---------------------
__global__ __launch_bounds__(256) void router_kernel(
    const float* __restrict__ x, const float* __restrict__ Wr,
    const float* __restrict__ br, int* __restrict__ topIdx,
    float* __restrict__ topGate)
{
    int n = blockIdx.x * 4 + (threadIdx.x >> 6);
    int lane = threadIdx.x & 63;
    const float4* xp = (const float4*)(x + (size_t)n * D_);
    float acc[E_];
#pragma unroll
    for (int e = 0; e < E_; e++) acc[e] = 0.f;
#pragma unroll
    for (int j = 0; j < 4; j++){
        int idx = j * 64 + lane;
        float4 xv = xp[idx];
#pragma unroll
        for (int e = 0; e < E_; e++){
            float4 wv = ((const float4*)(Wr + (size_t)e * D_))[idx];
            acc[e] += xv.x*wv.x + xv.y*wv.y + xv.z*wv.z + xv.w*wv.w;
        }
    }
#pragma unroll
    for (int e = 0; e < E_; e++){
        float v = acc[e];
        for (int off = 32; off > 0; off >>= 1) v += __shfl_xor(v, off, 64);
        acc[e] = v;
    }
    if (lane == 0){
        float best = -1e30f, second = -1e30f; int bi = 0, si = 0;
#pragma unroll
        for (int e = 0; e < E_; e++){
            float v = acc[e] + br[e];
            if (v > best){ second = best; si = bi; best = v; bi = e; }
            else if (v > second){ second = v; si = e; }
        }
        float e1 = __expf(second - best);
        float denom = 1.f + e1;
        topIdx[n*2+0] = bi;  topIdx[n*2+1] = si;
        topGate[n*2+0] = 1.f/denom;  topGate[n*2+1] = e1/denom;
    }
}

__global__ __launch_bounds__(256) void hist_kernel(
    const int* __restrict__ topIdx, int* __restrict__ hdr)
{
    __shared__ int c[E_];
    int t = threadIdx.x;
    if (t < E_) c[t] = 0;
    __syncthreads();
    int e = topIdx[blockIdx.x * 256 + t];
    atomicAdd(&c[e], 1);
    __syncthreads();
    if (t < E_) hdr[256 + blockIdx.x * E_ + t] = c[t];
}

__global__ __launch_bounds__(64) void scan2_kernel(int* __restrict__ hdr)
{
    __shared__ int cnt[32 * E_];
    __shared__ int tot[E_];
    __shared__ int offs[E_ + 1];
    int t = threadIdx.x;
    for (int i = t; i < 32 * E_; i += 64) cnt[i] = hdr[256 + i];
    __syncthreads();
    if (t < E_){
        int s = 0;
        for (int b = 0; b < 32; b++) s += cnt[b * E_ + t];
        tot[t] = s;
    }
    __syncthreads();
    if (t == 0){
        int o = 0;
        for (int e = 0; e < E_; e++){ offs[e] = o; o += tot[e]; }
        offs[E_] = o;
    }
    __syncthreads();
    if (t < E_ + 1) hdr[16 + t] = offs[t];
    if (t < E_){
        int run = offs[t];
        for (int b = 0; b < 32; b++){ hdr[512 + b * E_ + t] = run; run += cnt[b * E_ + t]; }
    }
    if (t == 0){
        int tn = 0;
        for (int e = 0; e < E_; e++){
            int nt = (tot[e] + BM - 1) >> 7;
            for (int i = 0; i < nt; i++){ hdr[32 + tn] = e; hdr[112 + tn] = offs[e] + (i << 7); tn++; }
        }
        for (; tn < MAXT; tn++){ hdr[32 + tn] = -1; hdr[112 + tn] = 0; }
    }
}

__global__ __launch_bounds__(256) void pos_kernel(
    const int* __restrict__ topIdx, const float* __restrict__ topGate,
    const int* __restrict__ hdr, int* __restrict__ posOf,
    int* __restrict__ rowTok, float* __restrict__ rowGate)
{
    __shared__ int c[E_];
    int t = threadIdx.x;
    if (t < E_) c[t] = 0;
    __syncthreads();
    int slot = blockIdx.x * 256 + t;
    int e = topIdx[slot];
    int r = atomicAdd(&c[e], 1);
    int pos = hdr[512 + blockIdx.x * E_ + e] + r;
    posOf[slot] = pos;
    rowTok[pos] = slot >> 1;
    rowGate[pos] = topGate[slot];
}

__global__ __launch_bounds__(256) void copy_kernel(
    const float* __restrict__ x, const int* __restrict__ posOf,
    unsigned short* __restrict__ xg)
{
    int slot = blockIdx.x * 4 + (threadIdx.x >> 6);
    int lane = threadIdx.x & 63;
    int n = slot >> 1;
    int pos = posOf[slot];
    const float4* xp = (const float4*)(x + (size_t)n * D_);
    ushort4* op = (ushort4*)(xg + (size_t)pos * D_);
#pragma unroll
    for (int j = 0; j < 4; j++){
        float4 v = xp[j * 64 + lane];
        ushort4 o; o.x=f2bf(v.x); o.y=f2bf(v.y); o.z=f2bf(v.z); o.w=f2bf(v.w);
        op[j * 64 + lane] = o;
    }
}

// ============================================================================
// 128x128 grouped GEMM: bf16 A (global_load_lds DMA) x fp32 W reg-staged to
// bf16 LDS.  Round-0 skeleton (fastest measured: 32 KB LDS, ~3 blocks/CU,
// double-buffered, 1 barrier/iter) + cvt-kernel elimination, WITHOUT round
// 6's fp32-LDS penalty:
//   - fp32 B tile in LDS has a 128B row stride == 32 banks -> ds_read_b128
//     is an 8-way bank conflict no XOR can fix (8.78M conflicts measured).
//     bf16 tile (64B stride) with g^((r>>1)&3) swizzle measured 0 conflicts.
//   - So: W fp32 -> registers (global_load_dwordx4, issued right after the
//     barrier = T14 issue-early), cvt_pk->bf16 and ds_write_b128 AFTER the
//     MFMA cluster (write-late). HBM latency and the cvt VALU hide under
//     MFMA; LDS stays bf16; ds_writes are tid-linear (0 conflicts).
//   - A path unchanged from round 0 (async DMA, swizzled source, 0 conflicts).
// MODE 1: hout = relu(A@W1^T+b1) bf16.  MODE 2: out[tok] += gate*(A@W2^T+b2).
// ============================================================================
template<int MODE>
__global__ __launch_bounds__(256) void moe_gemm(
    const unsigned short* __restrict__ A, int Ktot,
    const float* __restrict__ Wbase, size_t wStride,
    const float* __restrict__ biasBase, int biasStride,
    const int* __restrict__ hdr,
    const int* __restrict__ rowTok, const float* __restrict__ rowGate,
    unsigned short* __restrict__ hout, float* __restrict__ out)
{
    // dispatch-order swizzle: by fast within groups of 8 (A + W-slice locality)
    int gid = blockIdx.y * gridDim.x + blockIdx.x;
    int per = gridDim.x * 8;
    int g = gid / per, rr = gid % per;
    int by = g * 8 + (rr & 7);
    int bx = rr >> 3;

    int e = hdr[32 + bx];
    if (e < 0) return;
    int rowBase = hdr[112 + bx];
    int validRows = hdr[16 + e + 1] - rowBase;

    int kChunk = Ktot / gridDim.z;
    int kStart = blockIdx.z * kChunk;
    int nIter  = kChunk / BK;

    __shared__ __align__(16) unsigned short As[2][BM * BK];   // 2 x 8 KB
    __shared__ __align__(16) unsigned short Bs[2][BN * BK];   // 2 x 8 KB

    const float* biasE = biasBase + (size_t)e * biasStride + by * BN;

    const int tid  = threadIdx.x;
    const int lane = tid & 63, wave = tid >> 6;
    const int wm = wave & 1, wn = wave >> 1;
    const int l16 = lane & 15, quad = lane >> 4;

    const float* Wexp = Wbase + (size_t)e * wStride + (size_t)(by * BN) * Ktot;

    // A DMA descriptors: 2 x 16B bf16 granules per thread per K-tile
    size_t aOff[2]; int aS[2];
#pragma unroll
    for (int i = 0; i < 2; i++){
        int s = i * 256 + tid;
        int r = s >> 2, gst = s & 3;
        int gsrc = gst ^ ((r >> 1) & 3);
        int ar = rowBase + r;
        ar = ar < (NSLOT - 1) ? ar : (NSLOT - 1);   // clamp; junk masked later
        aOff[i] = (size_t)ar * Ktot + gsrc * 8;
        aS[i] = s * 16;
    }
    // B reg-staging descriptors: slot s -> row r=s>>2, phys granule gst=s&3
    // holding SOURCE granule gst^((r>>1)&3) (8 bf16 = 8 fp32 of W).
    const float* bSrc[2]; int bDst[2];
#pragma unroll
    for (int i = 0; i < 2; i++){
        int s = i * 256 + tid;
        int r = s >> 2, gst = s & 3;
        int gsrc = gst ^ ((r >> 1) & 3);
        bSrc[i] = Wexp + (size_t)r * Ktot + gsrc * 8;
        bDst[i] = s * 16;                           // tid-linear: 0 write conflicts
    }

    floatx4 acc[4][4];
#pragma unroll
    for (int mi = 0; mi < 4; mi++)
#pragma unroll
        for (int ni = 0; ni < 4; ni++)
            acc[mi][ni] = (floatx4){0.f,0.f,0.f,0.f};

    float4 w0a, w0b, w1a, w1b;   // in-flight W fp32 (4 x float4 = 32 VGPR)

    // prologue: tile 0
#pragma unroll
    for (int i = 0; i < 2; i++)
        async16(A + aOff[i] + kStart, (char*)As[0] + aS[i]);
    w0a = *(const float4*)(bSrc[0] + kStart);
    w0b = *(const float4*)(bSrc[0] + kStart + 4);
    w1a = *(const float4*)(bSrc[1] + kStart);
    w1b = *(const float4*)(bSrc[1] + kStart + 4);
    {
        union { short8 s; __hip_bfloat162 h[4]; } u;
        u.h[0] = __float22bfloat162_rn(make_float2(w0a.x, w0a.y));
        u.h[1] = __float22bfloat162_rn(make_float2(w0a.z, w0a.w));
        u.h[2] = __float22bfloat162_rn(make_float2(w0b.x, w0b.y));
        u.h[3] = __float22bfloat162_rn(make_float2(w0b.z, w0b.w));
        *(short8*)((char*)Bs[0] + bDst[0]) = u.s;
        u.h[0] = __float22bfloat162_rn(make_float2(w1a.x, w1a.y));
        u.h[1] = __float22bfloat162_rn(make_float2(w1a.z, w1a.w));
        u.h[2] = __float22bfloat162_rn(make_float2(w1b.x, w1b.y));
        u.h[3] = __float22bfloat162_rn(make_float2(w1b.z, w1b.w));
        *(short8*)((char*)Bs[0] + bDst[1]) = u.s;
    }

    for (int it = 0; it < nIter; it++){
        __syncthreads();                       // buffer p ready
        int p = it & 1;
        if (it + 1 < nIter){
            int kn = kStart + (it + 1) * BK;
            // issue-early: A DMA + W fp32 reg loads for tile it+1
#pragma unroll
            for (int i = 0; i < 2; i++)
                async16(A + aOff[i] + kn, (char*)As[p ^ 1] + aS[i]);
            w0a = *(const float4*)(bSrc[0] + kn);
            w0b = *(const float4*)(bSrc[0] + kn + 4);
            w1a = *(const float4*)(bSrc[1] + kn);
            w1b = *(const float4*)(bSrc[1] + kn + 4);
        }
        short8 af[4], bfr[4];
#pragma unroll
        for (int mi = 0; mi < 4; mi++){
            int r = wm*64 + mi*16 + l16;
            int gq = quad ^ ((r >> 1) & 3);
            af[mi] = *(const short8*)(As[p] + r * BK + gq * 8);
        }
#pragma unroll
        for (int ni = 0; ni < 4; ni++){
            int n = wn*64 + ni*16 + l16;
            int gq = quad ^ ((n >> 1) & 3);
            bfr[ni] = *(const short8*)(Bs[p] + n * BK + gq * 8);
        }
#pragma unroll
        for (int mi = 0; mi < 4; mi++)
#pragma unroll
            for (int ni = 0; ni < 4; ni++)
                acc[mi][ni] = __builtin_amdgcn_mfma_f32_16x16x32_bf16(
                    af[mi], bfr[ni], acc[mi][ni], 0, 0, 0);
        if (it + 1 < nIter){
            // write-late: cvt + bf16 ds_write into the other buffer
            union { short8 s; __hip_bfloat162 h[4]; } u;
            u.h[0] = __float22bfloat162_rn(make_float2(w0a.x, w0a.y));
            u.h[1] = __float22bfloat162_rn(make_float2(w0a.z, w0a.w));
            u.h[2] = __float22bfloat162_rn(make_float2(w0b.x, w0b.y));
            u.h[3] = __float22bfloat162_rn(make_float2(w0b.z, w0b.w));
            *(short8*)((char*)Bs[p ^ 1] + bDst[0]) = u.s;
            u.h[0] = __float22bfloat162_rn(make_float2(w1a.x, w1a.y));
            u.h[1] = __float22bfloat162_rn(make_float2(w1a.z, w1a.w));
            u.h[2] = __float22bfloat162_rn(make_float2(w1b.x, w1b.y));
            u.h[3] = __float22bfloat162_rn(make_float2(w1b.z, w1b.w));
            *(short8*)((char*)Bs[p ^ 1] + bDst[1]) = u.s;
        }
    }

    bool addB = (MODE == 1) || (blockIdx.z == 0);
#pragma unroll
    for (int mi = 0; mi < 4; mi++){
#pragma unroll
        for (int r = 0; r < 4; r++){
            int rl = wm*64 + mi*16 + quad*4 + r;
            if (rl >= validRows) continue;
            int grow = rowBase + rl;
            int   tok  = 0;
            float gate = 0.f;
            if (MODE == 2){ tok = rowTok[grow]; gate = rowGate[grow]; }
#pragma unroll
            for (int ni = 0; ni < 4; ni++){
                int lcol = wn*64 + ni*16 + l16;
                int gcol = by * BN + lcol;
                float v = acc[mi][ni][r] + (addB ? biasE[lcol] : 0.f);
                if (MODE == 1){
                    v = v > 0.f ? v : 0.f;
                    hout[(size_t)grow * H_ + gcol] = f2bf(v);
                } else {
                    atomicAdd(out + (size_t)tok * D_ + gcol, gate * v);
                }
            }
        }
    }
}

// ---------------- launch -----------------------------------------------------
extern "C" void kernel_launch(void* const* d_in, const int* in_sizes, int n_in,
                              void* d_out, int out_size, void* d_ws, size_t ws_size,
                              hipStream_t stream)
{
    (void)in_sizes; (void)n_in; (void)ws_size;
    const float* x  = (const float*)d_in[0];
    const float* Wr = (const float*)d_in[1];
    const float* br = (const float*)d_in[2];
    const float* W1 = (const float*)d_in[3];
    const float* b1 = (const float*)d_in[4];
    const float* W2 = (const float*)d_in[5];
    const float* b2 = (const float*)d_in[6];
    float* out = (float*)d_out;

    char* ws = (char*)d_ws;
    int*   hdr     = (int*)ws;
    int*   topIdx  = (int*)  (ws + 4096);
    float* topGate = (float*)(ws + 36864);
    int*   posOf   = (int*)  (ws + 69632);
    int*   rowTok  = (int*)  (ws + 102400);
    float* rowGate = (float*)(ws + 135168);
    unsigned short* xg   = (unsigned short*)(ws + 262144);     // 16.78 MB
    unsigned short* hbuf = (unsigned short*)(ws + 17039360);   // 67.1 MB -> ends 84.1 MB

    hipMemsetAsync(d_out, 0, (size_t)out_size * sizeof(float), stream);

    router_kernel<<<N_TOK/4, 256, 0, stream>>>(x, Wr, br, topIdx, topGate);
    hist_kernel<<<32, 256, 0, stream>>>(topIdx, hdr);
    scan2_kernel<<<1, 64, 0, stream>>>(hdr);
    pos_kernel<<<32, 256, 0, stream>>>(topIdx, topGate, hdr, posOf, rowTok, rowGate);
    copy_kernel<<<NSLOT/4, 256, 0, stream>>>(x, posOf, xg);

    // fp32 weights consumed directly (no cvt pass); converted in-register
    moe_gemm<1><<<dim3(MAXT, H_/BN, 1), 256, 0, stream>>>(
        xg, D_, W1, (size_t)H_ * D_, b1, H_, hdr, rowTok, rowGate, hbuf, nullptr);
    moe_gemm<2><<<dim3(MAXT, D_/BN, 2), 256, 0, stream>>>(
        hbuf, H_, W2, (size_t)D_ * H_, b2, D_, hdr, rowTok, rowGate, nullptr, out);
}